// Round 1
// baseline (1112.047 us; speedup 1.0000x reference)
//
#include <hip/hip_runtime.h>
#include <math.h>

#define D_  256
#define T_  2048
#define B_  4
#define M_  (B_*T_)
#define H_  4
#define HD_ 64

enum { OP_NONE=0, OP_SIGMUL=1, OP_ADDAUX=2, OP_AXPBY=3, OP_GELU=4, OP_TANHHALF=5 };

__device__ __forceinline__ float gelu_f(float x){ return 0.5f*x*(1.0f+erff(x*0.70710678118654752f)); }
__device__ __forceinline__ float sigmoid_f(float x){ return 1.0f/(1.0f+expf(-x)); }

// ---------------------------------------------------------------------------
// Generic fp32 GEMM: C[m, n] = sum_p A_p[m,:] . W_p[n,:] + bias[n], epilogue op
// M fixed = 8192. Tile 64x64, 256 threads, 4x4 microtile, BK=16.
// A_p row stride = K_p (all A buffers are contiguous). W_p row stride = ldw_p.
// aux (if used) has row stride 256.
// ---------------------------------------------------------------------------
__global__ __launch_bounds__(256) void gemm_k(
    const float* __restrict__ A0, const float* __restrict__ W0, int ldw0, int K0,
    const float* __restrict__ A1, const float* __restrict__ W1, int ldw1, int K1,
    const float* __restrict__ A2, const float* __restrict__ W2, int ldw2, int K2,
    const float* __restrict__ bias, const float* __restrict__ aux,
    float* __restrict__ C, int ldc, int op)
{
    __shared__ float As[16][68];
    __shared__ float Ws[16][68];
    const int row0 = blockIdx.y * 64;
    const int col0 = blockIdx.x * 64;
    const int tid  = threadIdx.x;
    const int tm = tid >> 4;        // 0..15
    const int tn = tid & 15;        // 0..15
    const int lr = tid >> 2;        // 0..63 load row
    const int lc = (tid & 3) * 4;   // 0,4,8,12 load col

    float acc[4][4];
    #pragma unroll
    for (int i=0;i<4;++i)
        #pragma unroll
        for (int j=0;j<4;++j) acc[i][j]=0.f;

    const float* Aps[3]={A0,A1,A2};
    const float* Wps[3]={W0,W1,W2};
    const int ldws[3]={ldw0,ldw1,ldw2};
    const int Kks[3]={K0,K1,K2};

    for (int p=0;p<3;++p){
        const float* A = Aps[p];
        if (!A) break;
        const float* W = Wps[p];
        const int K = Kks[p];
        const int ldw = ldws[p];
        const float* aRow = A + (size_t)(row0+lr)*K   + lc;
        const float* wRow = W + (size_t)(col0+lr)*ldw + lc;
        for (int kb=0; kb<K; kb+=16){
            float4 av = *(const float4*)(aRow + kb);
            float4 wv = *(const float4*)(wRow + kb);
            __syncthreads();   // previous inner loop done before overwriting LDS
            As[lc+0][lr]=av.x; As[lc+1][lr]=av.y; As[lc+2][lr]=av.z; As[lc+3][lr]=av.w;
            Ws[lc+0][lr]=wv.x; Ws[lc+1][lr]=wv.y; Ws[lc+2][lr]=wv.z; Ws[lc+3][lr]=wv.w;
            __syncthreads();
            #pragma unroll
            for (int k=0;k<16;++k){
                float4 a = *(const float4*)&As[k][tm*4];
                float4 w = *(const float4*)&Ws[k][tn*4];
                acc[0][0] += a.x*w.x; acc[0][1] += a.x*w.y; acc[0][2] += a.x*w.z; acc[0][3] += a.x*w.w;
                acc[1][0] += a.y*w.x; acc[1][1] += a.y*w.y; acc[1][2] += a.y*w.z; acc[1][3] += a.y*w.w;
                acc[2][0] += a.z*w.x; acc[2][1] += a.z*w.y; acc[2][2] += a.z*w.z; acc[2][3] += a.z*w.w;
                acc[3][0] += a.w*w.x; acc[3][1] += a.w*w.y; acc[3][2] += a.w*w.z; acc[3][3] += a.w*w.w;
            }
        }
    }

    const int nb = col0 + tn*4;
    const float b0=bias[nb+0], b1=bias[nb+1], b2=bias[nb+2], b3=bias[nb+3];
    #pragma unroll
    for (int i=0;i<4;++i){
        const int m = row0 + tm*4 + i;
        float v0=acc[i][0]+b0, v1=acc[i][1]+b1, v2=acc[i][2]+b2, v3=acc[i][3]+b3;
        if (op==OP_GELU){
            v0=gelu_f(v0); v1=gelu_f(v1); v2=gelu_f(v2); v3=gelu_f(v3);
        } else if (op==OP_TANHHALF){
            v0=0.5f*tanhf(v0); v1=0.5f*tanhf(v1); v2=0.5f*tanhf(v2); v3=0.5f*tanhf(v3);
        } else if (op!=OP_NONE){
            const float* ax = aux + (size_t)m*D_ + nb;
            float a0=ax[0], a1=ax[1], a2=ax[2], a3=ax[3];
            if (op==OP_SIGMUL){
                v0=a0*sigmoid_f(v0); v1=a1*sigmoid_f(v1); v2=a2*sigmoid_f(v2); v3=a3*sigmoid_f(v3);
            } else if (op==OP_ADDAUX){
                v0+=a0; v1+=a1; v2+=a2; v3+=a3;
            } else { // AXPBY: aux + 0.3*acc
                v0=a0+0.3f*v0; v1=a1+0.3f*v1; v2=a2+0.3f*v2; v3=a3+0.3f*v3;
            }
        }
        float4 outv; outv.x=v0; outv.y=v1; outv.z=v2; outv.w=v3;
        *(float4*)&C[(size_t)m*ldc + nb] = outv;
    }
}

// ---------------------------------------------------------------------------
// Depthwise causal conv, K=8, pad left 7.
// ---------------------------------------------------------------------------
__global__ __launch_bounds__(256) void conv_k(const float* __restrict__ X,
    const float* __restrict__ w, const float* __restrict__ bias, float* __restrict__ out)
{
    int idx = blockIdx.x*256 + threadIdx.x;           // over M_*D_
    int d = idx & (D_-1);
    int bt = idx >> 8;
    int t = bt & (T_-1);
    float acc = bias[d];
    const float* xp = X + (size_t)bt*D_ + d;
    const float* wp = w + d*8;
    #pragma unroll
    for (int j=0;j<8;++j){
        int tt = t - 7 + j;
        if (tt >= 0) acc += xp[(size_t)(j-7)*D_] * wp[j];
    }
    out[idx] = acc;
}

// ---------------------------------------------------------------------------
// Banded attention: window of 64 causal keys, per (b,h,32-query tile).
// QKVG layout per row (B*T, 1280): [q(256) k(256) v(256) gk(256) gv(256)]
// ---------------------------------------------------------------------------
#define QBLK 32
#define KROWS 95      // QBLK + 63
#define KSTR 68

__global__ __launch_bounds__(128) void attn_k(const float* __restrict__ QKVG, float* __restrict__ MED)
{
    __shared__ float Ks[KROWS][KSTR];
    __shared__ float Vs[KROWS][KSTR];
    const int b = blockIdx.z, h = blockIdx.y;
    const int t0 = blockIdx.x * QBLK;
    const int ks0 = t0 - 63;

    for (int i = threadIdx.x; i < KROWS*16; i += 128){
        int r = i >> 4, c = (i & 15) * 4;
        int kg = ks0 + r;
        float4 kv = {0.f,0.f,0.f,0.f}, vv = {0.f,0.f,0.f,0.f};
        if (kg >= 0){
            const float* base = QKVG + ((size_t)(b*T_ + kg))*1280 + 256 + h*HD_ + c;
            kv = *(const float4*)base;
            vv = *(const float4*)(base + 256);
        }
        *(float4*)&Ks[r][c] = kv;
        *(float4*)&Vs[r][c] = vv;
    }
    __syncthreads();

    const int qi  = threadIdx.x >> 2;   // 0..31
    const int sub = threadIdx.x & 3;    // 0..3 (16 dims each)
    const int q = t0 + qi;
    const float* qp = QKVG + ((size_t)(b*T_ + q))*1280 + h*HD_ + sub*16;
    float qv[16];
    #pragma unroll
    for (int j=0;j<16;j+=4){
        float4 t = *(const float4*)(qp+j);
        qv[j]=t.x; qv[j+1]=t.y; qv[j+2]=t.z; qv[j+3]=t.w;
    }
    float s[64];
    #pragma unroll
    for (int kk=0;kk<64;++kk){
        const float* kp = &Ks[qi+kk][sub*16];
        float p=0.f;
        #pragma unroll
        for (int j=0;j<16;++j) p += qv[j]*kp[j];
        p += __shfl_xor(p,1);
        p += __shfl_xor(p,2);
        int kg = q - 63 + kk;
        s[kk] = (kg>=0) ? p*0.125f : -1e30f;
    }
    float m = s[0];
    #pragma unroll
    for (int kk=1;kk<64;++kk) m = fmaxf(m, s[kk]);
    float l = 0.f;
    #pragma unroll
    for (int kk=0;kk<64;++kk){ float e = expf(s[kk]-m); s[kk]=e; l+=e; }
    float inv = 1.f/l;
    float o[16];
    #pragma unroll
    for (int j=0;j<16;++j) o[j]=0.f;
    #pragma unroll
    for (int kk=0;kk<64;++kk){
        const float p = s[kk];
        const float* vp = &Vs[qi+kk][sub*16];
        #pragma unroll
        for (int j=0;j<16;++j) o[j] += p*vp[j];
    }
    float* op = MED + ((size_t)(b*T_ + q))*D_ + h*HD_ + sub*16;
    #pragma unroll
    for (int j=0;j<16;j+=4){
        float4 t; t.x=o[j]*inv; t.y=o[j+1]*inv; t.z=o[j+2]*inv; t.w=o[j+3]*inv;
        *(float4*)(op+j)=t;
    }
}

// ---------------------------------------------------------------------------
// Scans: one thread per (b, d) channel, sequential over T.
// ---------------------------------------------------------------------------
__global__ void scan1_k(const float* __restrict__ QKVG, float* __restrict__ CONC)
{
    int idx = blockIdx.x*256 + threadIdx.x;  // 0..1023
    int d = idx & (D_-1), b = idx >> 8;
    const float* base = QKVG + (size_t)b*T_*1280;
    float sgk=0.f, sgkv=0.f;
    for (int t=0;t<T_;++t){
        float gk = base[(size_t)t*1280 + 768 + d];
        gk = gk > 0.f ? gk + 1.f : expf(gk);   // elu(x)+1
        float gv = base[(size_t)t*1280 + 1024 + d];
        sgk += gk; sgkv += gk*gv;
        CONC[((size_t)(b*T_ + t))*D_ + d] = sgkv / (sgk + 1e-5f);
    }
}

__global__ void scan2_k(const float* __restrict__ PR, float* __restrict__ GSUM, float* __restrict__ traj)
{
    int idx = blockIdx.x*256 + threadIdx.x;
    int d = idx & (D_-1), b = idx >> 8;
    float g = 0.f;
    for (int t=0;t<T_;++t){
        g = 0.9f*g + 0.1f*PR[((size_t)(b*T_ + t))*D_ + d];
        GSUM[((size_t)(b*T_ + t))*D_ + d] = g;
    }
    traj[b*D_ + d] = g;    // global_summary[:, -1, :]
}

__global__ void scan3_k(const float* __restrict__ SC, const float* __restrict__ SEQ, float* __restrict__ PRE3)
{
    int idx = blockIdx.x*256 + threadIdx.x;
    int d = idx & (D_-1), b = idx >> 8;
    float a = 0.f, dp = 1.f;
    const float ss = SEQ[b*D_ + d];
    for (int t=0;t<T_;++t){
        dp *= 0.9f;
        a = 0.9f*a + SC[((size_t)(b*T_ + t))*D_ + d];
        PRE3[((size_t)(b*T_ + t))*D_ + d] = fmaf(ss, dp, a);
    }
}

// ---------------------------------------------------------------------------
// LayerNorm: one wave per 256-wide row, 4 rows per 256-thread block.
// ---------------------------------------------------------------------------
__global__ __launch_bounds__(256) void ln_k(const float* __restrict__ in,
    const float* __restrict__ g, const float* __restrict__ b, float* __restrict__ out)
{
    int row  = blockIdx.x*4 + (threadIdx.x>>6);
    int lane = threadIdx.x & 63;
    const float* ip = in + (size_t)row*D_ + lane*4;
    float4 x = *(const float4*)ip;
    float s  = x.x+x.y+x.z+x.w;
    float s2 = x.x*x.x + x.y*x.y + x.z*x.z + x.w*x.w;
    #pragma unroll
    for (int o=1;o<64;o<<=1){ s += __shfl_xor(s,o); s2 += __shfl_xor(s2,o); }
    float mean = s * (1.f/256.f);
    float var  = s2 * (1.f/256.f) - mean*mean;
    float rs = rsqrtf(var + 1e-5f);
    int db = lane*4;
    float4 r;
    r.x=(x.x-mean)*rs*g[db+0]+b[db+0];
    r.y=(x.y-mean)*rs*g[db+1]+b[db+1];
    r.z=(x.z-mean)*rs*g[db+2]+b[db+2];
    r.w=(x.w-mean)*rs*g[db+3]+b[db+3];
    *(float4*)(out + (size_t)row*D_ + db) = r;
}

// LN3 (states) + LN4 on the last timestep row -> final_state
__global__ __launch_bounds__(256) void ln3_k(const float* __restrict__ in,
    const float* __restrict__ g3, const float* __restrict__ b3, float* __restrict__ states,
    const float* __restrict__ g4, const float* __restrict__ b4, float* __restrict__ fsout)
{
    int row  = blockIdx.x*4 + (threadIdx.x>>6);
    int lane = threadIdx.x & 63;
    const float* ip = in + (size_t)row*D_ + lane*4;
    float4 x = *(const float4*)ip;
    float s  = x.x+x.y+x.z+x.w;
    float s2 = x.x*x.x + x.y*x.y + x.z*x.z + x.w*x.w;
    #pragma unroll
    for (int o=1;o<64;o<<=1){ s += __shfl_xor(s,o); s2 += __shfl_xor(s2,o); }
    float mean = s * (1.f/256.f);
    float var  = s2 * (1.f/256.f) - mean*mean;
    float rs = rsqrtf(var + 1e-5f);
    int db = lane*4;
    float4 st;
    st.x=(x.x-mean)*rs*g3[db+0]+b3[db+0];
    st.y=(x.y-mean)*rs*g3[db+1]+b3[db+1];
    st.z=(x.z-mean)*rs*g3[db+2]+b3[db+2];
    st.w=(x.w-mean)*rs*g3[db+3]+b3[db+3];
    *(float4*)(states + (size_t)row*D_ + db) = st;

    if ((row & (T_-1)) == T_-1){
        float u  = st.x+st.y+st.z+st.w;
        float u2 = st.x*st.x + st.y*st.y + st.z*st.z + st.w*st.w;
        #pragma unroll
        for (int o=1;o<64;o<<=1){ u += __shfl_xor(u,o); u2 += __shfl_xor(u2,o); }
        float m2 = u * (1.f/256.f);
        float v2 = u2 * (1.f/256.f) - m2*m2;
        float r2 = rsqrtf(v2 + 1e-5f);
        float4 fs;
        fs.x=(st.x-m2)*r2*g4[db+0]+b4[db+0];
        fs.y=(st.y-m2)*r2*g4[db+1]+b4[db+1];
        fs.z=(st.z-m2)*r2*g4[db+2]+b4[db+2];
        fs.w=(st.w-m2)*r2*g4[db+3]+b4[db+3];
        *(float4*)(fsout + (size_t)(row>>11)*D_ + db) = fs;
    }
}

// ---------------------------------------------------------------------------
extern "C" void kernel_launch(void* const* d_in, const int* in_sizes, int n_in,
                              void* d_out, int out_size, void* d_ws, size_t ws_size,
                              hipStream_t stream)
{
    const float* X     = (const float*)d_in[0];
    const float* SEQ   = (const float*)d_in[1];
    const float* conv_w= (const float*)d_in[3];
    const float* conv_b= (const float*)d_in[4];
    const float* qkv_w = (const float*)d_in[5];
    const float* qkv_b = (const float*)d_in[6];
    const float* mo_w  = (const float*)d_in[7];
    const float* mo_b  = (const float*)d_in[8];
    const float* fg_w  = (const float*)d_in[9];
    const float* fg_b  = (const float*)d_in[10];
    const float* gkv_w = (const float*)d_in[11];
    const float* gkv_b = (const float*)d_in[12];
    const float* go_w  = (const float*)d_in[13];
    const float* go_b  = (const float*)d_in[14];
    const float* comb_w= (const float*)d_in[15];
    const float* comb_b= (const float*)d_in[16];
    const float* ffn1_w= (const float*)d_in[17];
    const float* ffn1_b= (const float*)d_in[18];
    const float* ffn2_w= (const float*)d_in[19];
    const float* ffn2_b= (const float*)d_in[20];
    const float* tr1_w = (const float*)d_in[21];
    const float* tr1_b = (const float*)d_in[22];
    const float* tr2_w = (const float*)d_in[23];
    const float* tr2_b = (const float*)d_in[24];
    const float* p2s_w = (const float*)d_in[25];
    const float* p2s_b = (const float*)d_in[26];
    const float* s2p_w = (const float*)d_in[27];
    const float* s2p_b = (const float*)d_in[28];
    const float* ln1_g = (const float*)d_in[29];
    const float* ln1_b = (const float*)d_in[30];
    const float* ln2_g = (const float*)d_in[31];
    const float* ln2_b = (const float*)d_in[32];
    const float* ln3_g = (const float*)d_in[33];
    const float* ln3_b = (const float*)d_in[34];
    const float* ln4_g = (const float*)d_in[35];
    const float* ln4_b = (const float*)d_in[36];

    float* ws   = (float*)d_ws;
    float* QKVG = ws;                          // M*1280  (reused later as H2: M*1024)
    float* H1   = QKVG + (size_t)M_*1280;      // M*512
    float* BUF2 = H1   + (size_t)M_*512;       // LH -> CS1 -> FFNIN
    float* BUF3 = BUF2 + (size_t)M_*256;       // MED -> MOUT -> SCALED -> PRE2
    float* BUF4 = BUF3 + (size_t)M_*256;       // MED2 -> PRE1 -> PRE3
    float* BUF5 = BUF4 + (size_t)M_*256;       // CONC -> PR
    float* BUF6 = BUF5 + (size_t)M_*256;       // GOUT -> GSUM -> STATES
    float* H2   = QKVG;

    float* out_pr = (float*)d_out;
    float* out_fs = out_pr + (size_t)M_*256;
    float* out_tj = out_fs + B_*256;

    const dim3 blk256(256), blk128(128);
    const int RT = M_/64;   // 128 row tiles

    // 1. qkv projection -> QKVG[:, 0:768)
    gemm_k<<<dim3(768/64, RT), blk256, 0, stream>>>(
        X, qkv_w, 256, 256,  nullptr,nullptr,0,0,  nullptr,nullptr,0,0,
        qkv_b, nullptr, QKVG, 1280, OP_NONE);
    // 2. gkv projection -> QKVG[:, 768:1280)
    gemm_k<<<dim3(512/64, RT), blk256, 0, stream>>>(
        X, gkv_w, 256, 256,  nullptr,nullptr,0,0,  nullptr,nullptr,0,0,
        gkv_b, nullptr, QKVG+768, 1280, OP_NONE);
    // 3. local_history (depthwise conv) -> BUF2
    conv_k<<<dim3(M_*D_/256), blk256, 0, stream>>>(X, conv_w, conv_b, BUF2);
    // 4. banded attention -> BUF3 (MED, pre-mo)
    attn_k<<<dim3(T_/QBLK, H_, B_), blk128, 0, stream>>>(QKVG, BUF3);
    // 5. mo projection: MED2 = MED@mo^T + b -> BUF4
    gemm_k<<<dim3(4, RT), blk256, 0, stream>>>(
        BUF3, mo_w, 256, 256,  nullptr,nullptr,0,0,  nullptr,nullptr,0,0,
        mo_b, nullptr, BUF4, 256, OP_NONE);
    // 6. concepts scan -> BUF5
    scan1_k<<<dim3(4), blk256, 0, stream>>>(QKVG, BUF5);
    // 7. global_out = concepts@go^T + b -> BUF6
    gemm_k<<<dim3(4, RT), blk256, 0, stream>>>(
        BUF5, go_w, 256, 256,  nullptr,nullptr,0,0,  nullptr,nullptr,0,0,
        go_b, nullptr, BUF6, 256, OP_NONE);
    // 8. medium_out = MED2 * sigmoid(X@fgx + MED2@fgm + b) -> BUF3
    gemm_k<<<dim3(4, RT), blk256, 0, stream>>>(
        X, fg_w, 512, 256,  BUF4, fg_w+256, 512, 256,  nullptr,nullptr,0,0,
        fg_b, BUF4, BUF3, 256, OP_SIGMUL);
    // 9. pre_ln1 = X + [LH,MOUT,GOUT]@comb^T + b -> BUF4
    gemm_k<<<dim3(4, RT), blk256, 0, stream>>>(
        BUF2, comb_w, 768, 256,  BUF3, comb_w+256, 768, 256,  BUF6, comb_w+512, 768, 256,
        comb_b, X, BUF4, 256, OP_ADDAUX);
    // 10. pr = LN1 -> BUF5
    ln_k<<<dim3(M_/4), blk256, 0, stream>>>(BUF4, ln1_g, ln1_b, BUF5);
    // 11. global_summary EMA -> BUF6, final_traj -> out
    scan2_k<<<dim3(4), blk256, 0, stream>>>(BUF5, BUF6, out_tj);
    // 12. cs1 = pr + 0.3*(pr@p2s^T + b) -> BUF2
    gemm_k<<<dim3(4, RT), blk256, 0, stream>>>(
        BUF5, p2s_w, 256, 256,  nullptr,nullptr,0,0,  nullptr,nullptr,0,0,
        p2s_b, BUF5, BUF2, 256, OP_AXPBY);
    // 13. H1 = gelu(cs1@tr1a + gsum@tr1b + b)
    gemm_k<<<dim3(8, RT), blk256, 0, stream>>>(
        BUF2, tr1_w, 512, 256,  BUF6, tr1_w+256, 512, 256,  nullptr,nullptr,0,0,
        tr1_b, nullptr, H1, 512, OP_GELU);
    // 14. scaled = 0.5*tanh(H1@tr2^T + b) -> BUF3
    gemm_k<<<dim3(4, RT), blk256, 0, stream>>>(
        H1, tr2_w, 512, 512,  nullptr,nullptr,0,0,  nullptr,nullptr,0,0,
        tr2_b, nullptr, BUF3, 256, OP_TANHHALF);
    // 15. state EMA + decayed initial -> BUF4 (pre_ln3)
    scan3_k<<<dim3(4), blk256, 0, stream>>>(BUF3, SEQ, BUF4);
    // 16. states = LN3 -> BUF6; final_state = LN4(states[-1]) -> out
    ln3_k<<<dim3(M_/4), blk256, 0, stream>>>(BUF4, ln3_g, ln3_b, BUF6, ln4_g, ln4_b, out_fs);
    // 17. ffn_in = pr + 0.3*(states@s2p^T + b) -> BUF2
    gemm_k<<<dim3(4, RT), blk256, 0, stream>>>(
        BUF6, s2p_w, 256, 256,  nullptr,nullptr,0,0,  nullptr,nullptr,0,0,
        s2p_b, BUF5, BUF2, 256, OP_AXPBY);
    // 18. H2 = gelu(ffn_in@ffn1^T + b)
    gemm_k<<<dim3(16, RT), blk256, 0, stream>>>(
        BUF2, ffn1_w, 256, 256,  nullptr,nullptr,0,0,  nullptr,nullptr,0,0,
        ffn1_b, nullptr, H2, 1024, OP_GELU);
    // 19. pre_ln2 = pr + H2@ffn2^T + b -> BUF3
    gemm_k<<<dim3(4, RT), blk256, 0, stream>>>(
        H2, ffn2_w, 1024, 1024,  nullptr,nullptr,0,0,  nullptr,nullptr,0,0,
        ffn2_b, BUF5, BUF3, 256, OP_ADDAUX);
    // 20. pr_out = LN2 -> d_out
    ln_k<<<dim3(M_/4), blk256, 0, stream>>>(BUF3, ln2_g, ln2_b, out_pr);
}

// Round 2
// 609.150 us; speedup vs baseline: 1.8256x; 1.8256x over previous
//
#include <hip/hip_runtime.h>
#include <math.h>

#define D_  256
#define T_  2048
#define B_  4
#define M_  (B_*T_)
#define H_  4
#define HD_ 64

#define NC_ 64          // scan chunks
#define LCH (T_/NC_)    // 32 steps per chunk

enum { OP_NONE=0, OP_SIGMUL=1, OP_ADDAUX=2, OP_AXPBY=3, OP_GELU=4, OP_TANHHALF=5 };

__device__ __forceinline__ float gelu_f(float x){ return 0.5f*x*(1.0f+erff(x*0.70710678118654752f)); }
__device__ __forceinline__ float sigmoid_f(float x){ return 1.0f/(1.0f+expf(-x)); }

// ---------------------------------------------------------------------------
// Generic fp32 GEMM: C[m, n] = sum_p A_p[m,:] . W_p[n,:] + bias[n], epilogue op
// M fixed = 8192. Tile 64x64, 256 threads, 4x4 microtile, BK=16.
// ---------------------------------------------------------------------------
__global__ __launch_bounds__(256) void gemm_k(
    const float* __restrict__ A0, const float* __restrict__ W0, int ldw0, int K0,
    const float* __restrict__ A1, const float* __restrict__ W1, int ldw1, int K1,
    const float* __restrict__ A2, const float* __restrict__ W2, int ldw2, int K2,
    const float* __restrict__ bias, const float* __restrict__ aux,
    float* __restrict__ C, int ldc, int op)
{
    __shared__ float As[16][68];
    __shared__ float Ws[16][68];
    const int row0 = blockIdx.y * 64;
    const int col0 = blockIdx.x * 64;
    const int tid  = threadIdx.x;
    const int tm = tid >> 4;        // 0..15
    const int tn = tid & 15;        // 0..15
    const int lr = tid >> 2;        // 0..63 load row
    const int lc = (tid & 3) * 4;   // 0,4,8,12 load col

    float acc[4][4];
    #pragma unroll
    for (int i=0;i<4;++i)
        #pragma unroll
        for (int j=0;j<4;++j) acc[i][j]=0.f;

    const float* Aps[3]={A0,A1,A2};
    const float* Wps[3]={W0,W1,W2};
    const int ldws[3]={ldw0,ldw1,ldw2};
    const int Kks[3]={K0,K1,K2};

    for (int p=0;p<3;++p){
        const float* A = Aps[p];
        if (!A) break;
        const float* W = Wps[p];
        const int K = Kks[p];
        const int ldw = ldws[p];
        const float* aRow = A + (size_t)(row0+lr)*K   + lc;
        const float* wRow = W + (size_t)(col0+lr)*ldw + lc;
        for (int kb=0; kb<K; kb+=16){
            float4 av = *(const float4*)(aRow + kb);
            float4 wv = *(const float4*)(wRow + kb);
            __syncthreads();
            As[lc+0][lr]=av.x; As[lc+1][lr]=av.y; As[lc+2][lr]=av.z; As[lc+3][lr]=av.w;
            Ws[lc+0][lr]=wv.x; Ws[lc+1][lr]=wv.y; Ws[lc+2][lr]=wv.z; Ws[lc+3][lr]=wv.w;
            __syncthreads();
            #pragma unroll
            for (int k=0;k<16;++k){
                float4 a = *(const float4*)&As[k][tm*4];
                float4 w = *(const float4*)&Ws[k][tn*4];
                acc[0][0] += a.x*w.x; acc[0][1] += a.x*w.y; acc[0][2] += a.x*w.z; acc[0][3] += a.x*w.w;
                acc[1][0] += a.y*w.x; acc[1][1] += a.y*w.y; acc[1][2] += a.y*w.z; acc[1][3] += a.y*w.w;
                acc[2][0] += a.z*w.x; acc[2][1] += a.z*w.y; acc[2][2] += a.z*w.z; acc[2][3] += a.z*w.w;
                acc[3][0] += a.w*w.x; acc[3][1] += a.w*w.y; acc[3][2] += a.w*w.z; acc[3][3] += a.w*w.w;
            }
        }
    }

    const int nb = col0 + tn*4;
    const float b0=bias[nb+0], b1=bias[nb+1], b2=bias[nb+2], b3=bias[nb+3];
    #pragma unroll
    for (int i=0;i<4;++i){
        const int m = row0 + tm*4 + i;
        float v0=acc[i][0]+b0, v1=acc[i][1]+b1, v2=acc[i][2]+b2, v3=acc[i][3]+b3;
        if (op==OP_GELU){
            v0=gelu_f(v0); v1=gelu_f(v1); v2=gelu_f(v2); v3=gelu_f(v3);
        } else if (op==OP_TANHHALF){
            v0=0.5f*tanhf(v0); v1=0.5f*tanhf(v1); v2=0.5f*tanhf(v2); v3=0.5f*tanhf(v3);
        } else if (op!=OP_NONE){
            const float* ax = aux + (size_t)m*D_ + nb;
            float a0=ax[0], a1=ax[1], a2=ax[2], a3=ax[3];
            if (op==OP_SIGMUL){
                v0=a0*sigmoid_f(v0); v1=a1*sigmoid_f(v1); v2=a2*sigmoid_f(v2); v3=a3*sigmoid_f(v3);
            } else if (op==OP_ADDAUX){
                v0+=a0; v1+=a1; v2+=a2; v3+=a3;
            } else { // AXPBY: aux + 0.3*acc
                v0=a0+0.3f*v0; v1=a1+0.3f*v1; v2=a2+0.3f*v2; v3=a3+0.3f*v3;
            }
        }
        float4 outv; outv.x=v0; outv.y=v1; outv.z=v2; outv.w=v3;
        *(float4*)&C[(size_t)m*ldc + nb] = outv;
    }
}

// ---------------------------------------------------------------------------
// Depthwise causal conv, K=8, pad left 7.
// ---------------------------------------------------------------------------
__global__ __launch_bounds__(256) void conv_k(const float* __restrict__ X,
    const float* __restrict__ w, const float* __restrict__ bias, float* __restrict__ out)
{
    int idx = blockIdx.x*256 + threadIdx.x;
    int d = idx & (D_-1);
    int bt = idx >> 8;
    int t = bt & (T_-1);
    float acc = bias[d];
    const float* xp = X + (size_t)bt*D_ + d;
    const float* wp = w + d*8;
    #pragma unroll
    for (int j=0;j<8;++j){
        int tt = t - 7 + j;
        if (tt >= 0) acc += xp[(size_t)(j-7)*D_] * wp[j];
    }
    out[idx] = acc;
}

// ---------------------------------------------------------------------------
// Banded attention: window of 64 causal keys, per (b,h,32-query tile).
// QKVG layout per row (B*T, 1280): [q(256) k(256) v(256) gk(256) gv(256)]
// ---------------------------------------------------------------------------
#define QBLK 32
#define KROWS 95      // QBLK + 63
#define KSTR 68

__global__ __launch_bounds__(128) void attn_k(const float* __restrict__ QKVG, float* __restrict__ MED)
{
    __shared__ float Ks[KROWS][KSTR];
    __shared__ float Vs[KROWS][KSTR];
    const int b = blockIdx.z, h = blockIdx.y;
    const int t0 = blockIdx.x * QBLK;
    const int ks0 = t0 - 63;

    for (int i = threadIdx.x; i < KROWS*16; i += 128){
        int r = i >> 4, c = (i & 15) * 4;
        int kg = ks0 + r;
        float4 kv = {0.f,0.f,0.f,0.f}, vv = {0.f,0.f,0.f,0.f};
        if (kg >= 0){
            const float* base = QKVG + ((size_t)(b*T_ + kg))*1280 + 256 + h*HD_ + c;
            kv = *(const float4*)base;
            vv = *(const float4*)(base + 256);
        }
        *(float4*)&Ks[r][c] = kv;
        *(float4*)&Vs[r][c] = vv;
    }
    __syncthreads();

    const int qi  = threadIdx.x >> 2;   // 0..31
    const int sub = threadIdx.x & 3;    // 0..3 (16 dims each)
    const int q = t0 + qi;
    const float* qp = QKVG + ((size_t)(b*T_ + q))*1280 + h*HD_ + sub*16;
    float qv[16];
    #pragma unroll
    for (int j=0;j<16;j+=4){
        float4 t = *(const float4*)(qp+j);
        qv[j]=t.x; qv[j+1]=t.y; qv[j+2]=t.z; qv[j+3]=t.w;
    }
    float s[64];
    #pragma unroll
    for (int kk=0;kk<64;++kk){
        const float* kp = &Ks[qi+kk][sub*16];
        float p=0.f;
        #pragma unroll
        for (int j=0;j<16;++j) p += qv[j]*kp[j];
        p += __shfl_xor(p,1);
        p += __shfl_xor(p,2);
        int kg = q - 63 + kk;
        s[kk] = (kg>=0) ? p*0.125f : -1e30f;
    }
    float m = s[0];
    #pragma unroll
    for (int kk=1;kk<64;++kk) m = fmaxf(m, s[kk]);
    float l = 0.f;
    #pragma unroll
    for (int kk=0;kk<64;++kk){ float e = expf(s[kk]-m); s[kk]=e; l+=e; }
    float inv = 1.f/l;
    float o[16];
    #pragma unroll
    for (int j=0;j<16;++j) o[j]=0.f;
    #pragma unroll
    for (int kk=0;kk<64;++kk){
        const float p = s[kk];
        const float* vp = &Vs[qi+kk][sub*16];
        #pragma unroll
        for (int j=0;j<16;++j) o[j] += p*vp[j];
    }
    float* op = MED + ((size_t)(b*T_ + q))*D_ + h*HD_ + sub*16;
    #pragma unroll
    for (int j=0;j<16;j+=4){
        float4 t; t.x=o[j]*inv; t.y=o[j+1]*inv; t.z=o[j+2]*inv; t.w=o[j+3]*inv;
        *(float4*)(op+j)=t;
    }
}

// ---------------------------------------------------------------------------
// Chunked parallel scans. T split into NC_ chunks of LCH.
// pass1: per-chunk carry aggregates. pass2: tiny sequential prefix over
// chunk carries (exclusive). pass3: replay recurrence with correct carry-in.
// ---------------------------------------------------------------------------

// --- scan1: concepts = cumsum(gk*gv) / (cumsum(gk)+eps) --------------------
__global__ __launch_bounds__(256) void scan1_p1(const float* __restrict__ QKVG,
    float* __restrict__ CA, float* __restrict__ CC)
{
    const int d = threadIdx.x, c = blockIdx.x, b = blockIdx.y;
    const float* base = QKVG + ((size_t)(b*T_ + c*LCH))*1280;
    float sgk=0.f, sgkv=0.f;
    for (int t=0;t<LCH;++t){
        float gk = base[(size_t)t*1280 + 768 + d];
        gk = gk > 0.f ? gk + 1.f : expf(gk);
        float gv = base[(size_t)t*1280 + 1024 + d];
        sgk += gk; sgkv += gk*gv;
    }
    CA[((size_t)b*NC_ + c)*D_ + d] = sgk;
    CC[((size_t)b*NC_ + c)*D_ + d] = sgkv;
}

__global__ void scan1_p2(float* __restrict__ CA, float* __restrict__ CC)
{
    int idx = blockIdx.x*256 + threadIdx.x;   // 1024 (b,d) pairs
    int d = idx & (D_-1), b = idx >> 8;
    float sa=0.f, sc=0.f;
    for (int c=0;c<NC_;++c){
        size_t o = ((size_t)b*NC_ + c)*D_ + d;
        float a = CA[o], cc = CC[o];
        CA[o] = sa; CC[o] = sc;
        sa += a; sc += cc;
    }
}

__global__ __launch_bounds__(256) void scan1_p3(const float* __restrict__ QKVG,
    const float* __restrict__ CA, const float* __restrict__ CC, float* __restrict__ CONC)
{
    const int d = threadIdx.x, c = blockIdx.x, b = blockIdx.y;
    float sgk  = CA[((size_t)b*NC_ + c)*D_ + d];
    float sgkv = CC[((size_t)b*NC_ + c)*D_ + d];
    const float* base = QKVG + ((size_t)(b*T_ + c*LCH))*1280;
    float* out = CONC + ((size_t)(b*T_ + c*LCH))*D_ + d;
    for (int t=0;t<LCH;++t){
        float gk = base[(size_t)t*1280 + 768 + d];
        gk = gk > 0.f ? gk + 1.f : expf(gk);
        float gv = base[(size_t)t*1280 + 1024 + d];
        sgk += gk; sgkv += gk*gv;
        out[(size_t)t*D_] = sgkv / (sgk + 1e-5f);
    }
}

// --- EMA scans: g[t] = 0.9*g[t-1] + alpha*x[t] -----------------------------
__global__ __launch_bounds__(256) void ema_p1(const float* __restrict__ X,
    float* __restrict__ CARRY, float alpha)
{
    const int d = threadIdx.x, c = blockIdx.x, b = blockIdx.y;
    const float* xp = X + ((size_t)(b*T_ + c*LCH))*D_ + d;
    float g = 0.f;
    for (int t=0;t<LCH;++t) g = 0.9f*g + alpha*xp[(size_t)t*D_];
    CARRY[((size_t)b*NC_ + c)*D_ + d] = g;
}

__global__ void ema_p2(float* __restrict__ CARRY, float* __restrict__ traj)
{
    int idx = blockIdx.x*256 + threadIdx.x;
    int d = idx & (D_-1), b = idx >> 8;
    const float dL = powf(0.9f, (float)LCH);
    float run = 0.f;
    for (int c=0;c<NC_;++c){
        size_t o = ((size_t)b*NC_ + c)*D_ + d;
        float loc = CARRY[o];
        CARRY[o] = run;                 // exclusive carry-in for chunk c
        run = loc + dL*run;
    }
    if (traj) traj[b*D_ + d] = run;     // value at t = T-1
}

__global__ __launch_bounds__(256) void ema_p3(const float* __restrict__ X,
    const float* __restrict__ CARRY, float* __restrict__ OUT, float alpha)
{
    const int d = threadIdx.x, c = blockIdx.x, b = blockIdx.y;
    float g = CARRY[((size_t)b*NC_ + c)*D_ + d];
    const float* xp = X + ((size_t)(b*T_ + c*LCH))*D_ + d;
    float* op = OUT + ((size_t)(b*T_ + c*LCH))*D_ + d;
    for (int t=0;t<LCH;++t){
        g = 0.9f*g + alpha*xp[(size_t)t*D_];
        op[(size_t)t*D_] = g;
    }
}

// scan3 variant: adds analytic sequential_state * 0.9^(t+1)
__global__ __launch_bounds__(256) void ema_p3_state(const float* __restrict__ X,
    const float* __restrict__ CARRY, const float* __restrict__ SEQ, float* __restrict__ OUT)
{
    const int d = threadIdx.x, c = blockIdx.x, b = blockIdx.y;
    float a = CARRY[((size_t)b*NC_ + c)*D_ + d];
    const float ss = SEQ[b*D_ + d];
    float dp = powf(0.9f, (float)(c*LCH + 1));
    const float* xp = X + ((size_t)(b*T_ + c*LCH))*D_ + d;
    float* op = OUT + ((size_t)(b*T_ + c*LCH))*D_ + d;
    for (int t=0;t<LCH;++t){
        a = 0.9f*a + xp[(size_t)t*D_];
        op[(size_t)t*D_] = fmaf(ss, dp, a);
        dp *= 0.9f;
    }
}

// ---------------------------------------------------------------------------
// LayerNorm: one wave per 256-wide row, 4 rows per 256-thread block.
// ---------------------------------------------------------------------------
__global__ __launch_bounds__(256) void ln_k(const float* __restrict__ in,
    const float* __restrict__ g, const float* __restrict__ b, float* __restrict__ out)
{
    int row  = blockIdx.x*4 + (threadIdx.x>>6);
    int lane = threadIdx.x & 63;
    const float* ip = in + (size_t)row*D_ + lane*4;
    float4 x = *(const float4*)ip;
    float s  = x.x+x.y+x.z+x.w;
    float s2 = x.x*x.x + x.y*x.y + x.z*x.z + x.w*x.w;
    #pragma unroll
    for (int o=1;o<64;o<<=1){ s += __shfl_xor(s,o); s2 += __shfl_xor(s2,o); }
    float mean = s * (1.f/256.f);
    float var  = s2 * (1.f/256.f) - mean*mean;
    float rs = rsqrtf(var + 1e-5f);
    int db = lane*4;
    float4 r;
    r.x=(x.x-mean)*rs*g[db+0]+b[db+0];
    r.y=(x.y-mean)*rs*g[db+1]+b[db+1];
    r.z=(x.z-mean)*rs*g[db+2]+b[db+2];
    r.w=(x.w-mean)*rs*g[db+3]+b[db+3];
    *(float4*)(out + (size_t)row*D_ + db) = r;
}

// LN3 (states) + LN4 on the last timestep row -> final_state
__global__ __launch_bounds__(256) void ln3_k(const float* __restrict__ in,
    const float* __restrict__ g3, const float* __restrict__ b3, float* __restrict__ states,
    const float* __restrict__ g4, const float* __restrict__ b4, float* __restrict__ fsout)
{
    int row  = blockIdx.x*4 + (threadIdx.x>>6);
    int lane = threadIdx.x & 63;
    const float* ip = in + (size_t)row*D_ + lane*4;
    float4 x = *(const float4*)ip;
    float s  = x.x+x.y+x.z+x.w;
    float s2 = x.x*x.x + x.y*x.y + x.z*x.z + x.w*x.w;
    #pragma unroll
    for (int o=1;o<64;o<<=1){ s += __shfl_xor(s,o); s2 += __shfl_xor(s2,o); }
    float mean = s * (1.f/256.f);
    float var  = s2 * (1.f/256.f) - mean*mean;
    float rs = rsqrtf(var + 1e-5f);
    int db = lane*4;
    float4 st;
    st.x=(x.x-mean)*rs*g3[db+0]+b3[db+0];
    st.y=(x.y-mean)*rs*g3[db+1]+b3[db+1];
    st.z=(x.z-mean)*rs*g3[db+2]+b3[db+2];
    st.w=(x.w-mean)*rs*g3[db+3]+b3[db+3];
    *(float4*)(states + (size_t)row*D_ + db) = st;

    if ((row & (T_-1)) == T_-1){
        float u  = st.x+st.y+st.z+st.w;
        float u2 = st.x*st.x + st.y*st.y + st.z*st.z + st.w*st.w;
        #pragma unroll
        for (int o=1;o<64;o<<=1){ u += __shfl_xor(u,o); u2 += __shfl_xor(u2,o); }
        float m2 = u * (1.f/256.f);
        float v2 = u2 * (1.f/256.f) - m2*m2;
        float r2 = rsqrtf(v2 + 1e-5f);
        float4 fs;
        fs.x=(st.x-m2)*r2*g4[db+0]+b4[db+0];
        fs.y=(st.y-m2)*r2*g4[db+1]+b4[db+1];
        fs.z=(st.z-m2)*r2*g4[db+2]+b4[db+2];
        fs.w=(st.w-m2)*r2*g4[db+3]+b4[db+3];
        *(float4*)(fsout + (size_t)(row>>11)*D_ + db) = fs;
    }
}

// ---------------------------------------------------------------------------
extern "C" void kernel_launch(void* const* d_in, const int* in_sizes, int n_in,
                              void* d_out, int out_size, void* d_ws, size_t ws_size,
                              hipStream_t stream)
{
    const float* X     = (const float*)d_in[0];
    const float* SEQ   = (const float*)d_in[1];
    const float* conv_w= (const float*)d_in[3];
    const float* conv_b= (const float*)d_in[4];
    const float* qkv_w = (const float*)d_in[5];
    const float* qkv_b = (const float*)d_in[6];
    const float* mo_w  = (const float*)d_in[7];
    const float* mo_b  = (const float*)d_in[8];
    const float* fg_w  = (const float*)d_in[9];
    const float* fg_b  = (const float*)d_in[10];
    const float* gkv_w = (const float*)d_in[11];
    const float* gkv_b = (const float*)d_in[12];
    const float* go_w  = (const float*)d_in[13];
    const float* go_b  = (const float*)d_in[14];
    const float* comb_w= (const float*)d_in[15];
    const float* comb_b= (const float*)d_in[16];
    const float* ffn1_w= (const float*)d_in[17];
    const float* ffn1_b= (const float*)d_in[18];
    const float* ffn2_w= (const float*)d_in[19];
    const float* ffn2_b= (const float*)d_in[20];
    const float* tr1_w = (const float*)d_in[21];
    const float* tr1_b = (const float*)d_in[22];
    const float* tr2_w = (const float*)d_in[23];
    const float* tr2_b = (const float*)d_in[24];
    const float* p2s_w = (const float*)d_in[25];
    const float* p2s_b = (const float*)d_in[26];
    const float* s2p_w = (const float*)d_in[27];
    const float* s2p_b = (const float*)d_in[28];
    const float* ln1_g = (const float*)d_in[29];
    const float* ln1_b = (const float*)d_in[30];
    const float* ln2_g = (const float*)d_in[31];
    const float* ln2_b = (const float*)d_in[32];
    const float* ln3_g = (const float*)d_in[33];
    const float* ln3_b = (const float*)d_in[34];
    const float* ln4_g = (const float*)d_in[35];
    const float* ln4_b = (const float*)d_in[36];

    float* ws   = (float*)d_ws;
    float* QKVG = ws;                          // M*1280  (reused later as H2: M*1024)
    float* H1   = QKVG + (size_t)M_*1280;      // M*512   (also aliased as scan-carry space)
    float* BUF2 = H1   + (size_t)M_*512;       // LH -> CS1 -> FFNIN
    float* BUF3 = BUF2 + (size_t)M_*256;       // MED -> MOUT -> SCALED -> PRE2
    float* BUF4 = BUF3 + (size_t)M_*256;       // MED2 -> PRE1 -> PRE3
    float* BUF5 = BUF4 + (size_t)M_*256;       // CONC -> PR
    float* BUF6 = BUF5 + (size_t)M_*256;       // GOUT -> GSUM -> STATES
    float* H2   = QKVG;

    // scan carry buffers alias H1 (H1 is only live for steps 13-14)
    float* CAR0 = H1;                          // B*NC*D
    float* CAR1 = H1 + (size_t)B_*NC_*D_;      // B*NC*D

    float* out_pr = (float*)d_out;
    float* out_fs = out_pr + (size_t)M_*256;
    float* out_tj = out_fs + B_*256;

    const dim3 blk256(256), blk128(128);
    const dim3 scan_grid(NC_, B_);
    const int RT = M_/64;   // 128 row tiles

    // 1. qkv projection -> QKVG[:, 0:768)
    gemm_k<<<dim3(768/64, RT), blk256, 0, stream>>>(
        X, qkv_w, 256, 256,  nullptr,nullptr,0,0,  nullptr,nullptr,0,0,
        qkv_b, nullptr, QKVG, 1280, OP_NONE);
    // 2. gkv projection -> QKVG[:, 768:1280)
    gemm_k<<<dim3(512/64, RT), blk256, 0, stream>>>(
        X, gkv_w, 256, 256,  nullptr,nullptr,0,0,  nullptr,nullptr,0,0,
        gkv_b, nullptr, QKVG+768, 1280, OP_NONE);
    // 3. local_history (depthwise conv) -> BUF2
    conv_k<<<dim3(M_*D_/256), blk256, 0, stream>>>(X, conv_w, conv_b, BUF2);
    // 4. banded attention -> BUF3 (MED, pre-mo)
    attn_k<<<dim3(T_/QBLK, H_, B_), blk128, 0, stream>>>(QKVG, BUF3);
    // 5. mo projection: MED2 = MED@mo^T + b -> BUF4
    gemm_k<<<dim3(4, RT), blk256, 0, stream>>>(
        BUF3, mo_w, 256, 256,  nullptr,nullptr,0,0,  nullptr,nullptr,0,0,
        mo_b, nullptr, BUF4, 256, OP_NONE);
    // 6. concepts scan (chunked) -> BUF5
    scan1_p1<<<scan_grid, blk256, 0, stream>>>(QKVG, CAR0, CAR1);
    scan1_p2<<<dim3(4), blk256, 0, stream>>>(CAR0, CAR1);
    scan1_p3<<<scan_grid, blk256, 0, stream>>>(QKVG, CAR0, CAR1, BUF5);
    // 7. global_out = concepts@go^T + b -> BUF6
    gemm_k<<<dim3(4, RT), blk256, 0, stream>>>(
        BUF5, go_w, 256, 256,  nullptr,nullptr,0,0,  nullptr,nullptr,0,0,
        go_b, nullptr, BUF6, 256, OP_NONE);
    // 8. medium_out = MED2 * sigmoid(X@fgx + MED2@fgm + b) -> BUF3
    gemm_k<<<dim3(4, RT), blk256, 0, stream>>>(
        X, fg_w, 512, 256,  BUF4, fg_w+256, 512, 256,  nullptr,nullptr,0,0,
        fg_b, BUF4, BUF3, 256, OP_SIGMUL);
    // 9. pre_ln1 = X + [LH,MOUT,GOUT]@comb^T + b -> BUF4
    gemm_k<<<dim3(4, RT), blk256, 0, stream>>>(
        BUF2, comb_w, 768, 256,  BUF3, comb_w+256, 768, 256,  BUF6, comb_w+512, 768, 256,
        comb_b, X, BUF4, 256, OP_ADDAUX);
    // 10. pr = LN1 -> BUF5
    ln_k<<<dim3(M_/4), blk256, 0, stream>>>(BUF4, ln1_g, ln1_b, BUF5);
    // 11. global_summary EMA (chunked) -> BUF6, final_traj -> out
    ema_p1<<<scan_grid, blk256, 0, stream>>>(BUF5, CAR0, 0.1f);
    ema_p2<<<dim3(4), blk256, 0, stream>>>(CAR0, out_tj);
    ema_p3<<<scan_grid, blk256, 0, stream>>>(BUF5, CAR0, BUF6, 0.1f);
    // 12. cs1 = pr + 0.3*(pr@p2s^T + b) -> BUF2
    gemm_k<<<dim3(4, RT), blk256, 0, stream>>>(
        BUF5, p2s_w, 256, 256,  nullptr,nullptr,0,0,  nullptr,nullptr,0,0,
        p2s_b, BUF5, BUF2, 256, OP_AXPBY);
    // 13. H1 = gelu(cs1@tr1a + gsum@tr1b + b)
    gemm_k<<<dim3(8, RT), blk256, 0, stream>>>(
        BUF2, tr1_w, 512, 256,  BUF6, tr1_w+256, 512, 256,  nullptr,nullptr,0,0,
        tr1_b, nullptr, H1, 512, OP_GELU);
    // 14. scaled = 0.5*tanh(H1@tr2^T + b) -> BUF3
    gemm_k<<<dim3(4, RT), blk256, 0, stream>>>(
        H1, tr2_w, 512, 512,  nullptr,nullptr,0,0,  nullptr,nullptr,0,0,
        tr2_b, nullptr, BUF3, 256, OP_TANHHALF);
    // 15. state EMA + decayed initial (chunked) -> BUF4 (pre_ln3)
    //     (H1 is dead again from here on; reuse as carry space)
    ema_p1<<<scan_grid, blk256, 0, stream>>>(BUF3, CAR0, 1.0f);
    ema_p2<<<dim3(4), blk256, 0, stream>>>(CAR0, nullptr);
    ema_p3_state<<<scan_grid, blk256, 0, stream>>>(BUF3, CAR0, SEQ, BUF4);
    // 16. states = LN3 -> BUF6; final_state = LN4(states[-1]) -> out
    ln3_k<<<dim3(M_/4), blk256, 0, stream>>>(BUF4, ln3_g, ln3_b, BUF6, ln4_g, ln4_b, out_fs);
    // 17. ffn_in = pr + 0.3*(states@s2p^T + b) -> BUF2
    gemm_k<<<dim3(4, RT), blk256, 0, stream>>>(
        BUF6, s2p_w, 256, 256,  nullptr,nullptr,0,0,  nullptr,nullptr,0,0,
        s2p_b, BUF5, BUF2, 256, OP_AXPBY);
    // 18. H2 = gelu(ffn_in@ffn1^T + b)
    gemm_k<<<dim3(16, RT), blk256, 0, stream>>>(
        BUF2, ffn1_w, 256, 256,  nullptr,nullptr,0,0,  nullptr,nullptr,0,0,
        ffn1_b, nullptr, H2, 1024, OP_GELU);
    // 19. pre_ln2 = pr + H2@ffn2^T + b -> BUF3
    gemm_k<<<dim3(4, RT), blk256, 0, stream>>>(
        H2, ffn2_w, 1024, 1024,  nullptr,nullptr,0,0,  nullptr,nullptr,0,0,
        ffn2_b, BUF5, BUF3, 256, OP_ADDAUX);
    // 20. pr_out = LN2 -> d_out
    ln_k<<<dim3(M_/4), blk256, 0, stream>>>(BUF3, ln2_g, ln2_b, out_pr);
}

// Round 3
// 376.570 us; speedup vs baseline: 2.9531x; 1.6176x over previous
//
#include <hip/hip_runtime.h>
#include <hip/hip_bf16.h>
#include <math.h>

#define D_  256
#define T_  2048
#define B_  4
#define M_  (B_*T_)
#define H_  4
#define HD_ 64

#define NC_ 64          // scan chunks
#define LCH (T_/NC_)    // 32 steps per chunk

enum { OP_NONE=0, OP_SIGMUL=1, OP_ADDAUX=2, OP_AXPBY=3, OP_GELU=4, OP_TANHHALF=5 };

typedef short short8 __attribute__((ext_vector_type(8)));
typedef float f32x4  __attribute__((ext_vector_type(4)));

__device__ __forceinline__ float gelu_f(float x){ return 0.5f*x*(1.0f+erff(x*0.70710678118654752f)); }
__device__ __forceinline__ float sigmoid_f(float x){ return 1.0f/(1.0f+expf(-x)); }

// pack 2 fp32 -> 2 bf16 (RNE) in one uint (low ushort = a, high = b)
__device__ __forceinline__ unsigned pk2(float a, float b){
    __hip_bfloat162 h = __float22bfloat162_rn(make_float2(a,b));
    union { __hip_bfloat162 h; unsigned u; } c; c.h = h; return c.u;
}
__device__ __forceinline__ float bf_lo(unsigned u){ return __uint_as_float(u << 16); }
__device__ __forceinline__ float bf_hi(unsigned u){ return __uint_as_float(u & 0xffff0000u); }

// ---------------------------------------------------------------------------
// bf16 MFMA GEMM: C[m,n] = sum_p A_p[m,:] . W_p[n,:] + bias[n], epilogue op.
// M = 8192. Block tile 64x64, BK=64, 256 threads = 4 waves (2x2), each wave
// 32x32 via 2x2 fragments of mfma_f32_16x16x32_bf16. fp32 global -> bf16 LDS
// (RNE) with XOR swizzle; fp32 accumulate; XCD-chunked block swizzle.
// ---------------------------------------------------------------------------
__global__ __launch_bounds__(256) void gemm_k(
    const float* __restrict__ A0, const float* __restrict__ W0, int ldw0, int K0,
    const float* __restrict__ A1, const float* __restrict__ W1, int ldw1, int K1,
    const float* __restrict__ A2, const float* __restrict__ W2, int ldw2, int K2,
    const float* __restrict__ bias, const float* __restrict__ aux,
    float* __restrict__ C, int ldc, int op, int ncol)
{
    __shared__ unsigned short As[64*64];
    __shared__ unsigned short Ws[64*64];

    // XCD-chunked swizzle (nwg % 8 == 0 always: nrow=128)
    const int q8   = gridDim.x >> 3;
    const int lid  = (blockIdx.x & 7)*q8 + (blockIdx.x >> 3);
    const int brow = lid / ncol;
    const int bcol = lid - brow*ncol;
    const int row0 = brow*64, col0 = bcol*64;

    const int tid  = threadIdx.x;
    const int lane = tid & 63, wid = tid >> 6;
    const int wm = (wid >> 1)*32, wn = (wid & 1)*32;
    const int l15 = lane & 15, l4 = lane >> 4;

    f32x4 acc[2][2];
    #pragma unroll
    for (int i=0;i<2;++i)
        #pragma unroll
        for (int j=0;j<2;++j) acc[i][j] = (f32x4){0.f,0.f,0.f,0.f};

    const float* Aps[3]={A0,A1,A2};
    const float* Wps[3]={W0,W1,W2};
    const int ldws[3]={ldw0,ldw1,ldw2};
    const int Kks[3]={K0,K1,K2};

    const int srow = tid >> 3;          // staging row (two reps: +32)
    const int sc8  = (tid & 7) * 8;     // k-offset within tile (8 elems)

    for (int p=0;p<3;++p){
        const float* A = Aps[p];
        if (!A) break;
        const float* W = Wps[p];
        const int K = Kks[p];
        const int ldw = ldws[p];
        for (int kb=0; kb<K; kb+=64){
            __syncthreads();  // previous MFMA phase done before LDS overwrite
            #pragma unroll
            for (int rep=0;rep<2;++rep){
                const int row = srow + rep*32;
                const float* ga = A + (size_t)(row0+row)*K + kb + sc8;
                float4 a0 = *(const float4*)ga;
                float4 a1 = *(const float4*)(ga+4);
                uint4 pa = { pk2(a0.x,a0.y), pk2(a0.z,a0.w), pk2(a1.x,a1.y), pk2(a1.z,a1.w) };
                const int ia = (row*64 + sc8) ^ ((row&7)<<3);
                *(uint4*)&As[ia] = pa;
                const float* gw = W + (size_t)(col0+row)*ldw + kb + sc8;
                float4 w0 = *(const float4*)gw;
                float4 w1 = *(const float4*)(gw+4);
                uint4 pw = { pk2(w0.x,w0.y), pk2(w0.z,w0.w), pk2(w1.x,w1.y), pk2(w1.z,w1.w) };
                *(uint4*)&Ws[ia] = pw;
            }
            __syncthreads();
            #pragma unroll
            for (int ks=0;ks<2;++ks){
                const int koff = ks*32 + l4*8;
                short8 af[2], bf[2];
                #pragma unroll
                for (int f=0;f<2;++f){
                    const int ar = wm + f*16 + l15;
                    af[f] = *(const short8*)&As[(ar*64 + koff) ^ ((ar&7)<<3)];
                    const int brn = wn + f*16 + l15;
                    bf[f] = *(const short8*)&Ws[(brn*64 + koff) ^ ((brn&7)<<3)];
                }
                #pragma unroll
                for (int fm=0;fm<2;++fm)
                    #pragma unroll
                    for (int fn=0;fn<2;++fn)
                        acc[fm][fn] = __builtin_amdgcn_mfma_f32_16x16x32_bf16(
                            af[fm], bf[fn], acc[fm][fn], 0, 0, 0);
            }
        }
    }

    // epilogue: D mapping col = lane&15, row = (lane>>4)*4 + j
    #pragma unroll
    for (int fn=0;fn<2;++fn){
        const int n = col0 + wn + fn*16 + l15;
        const float bv = bias[n];
        #pragma unroll
        for (int fm=0;fm<2;++fm){
            #pragma unroll
            for (int j=0;j<4;++j){
                const int m = row0 + wm + fm*16 + l4*4 + j;
                float v = acc[fm][fn][j] + bv;
                if (op==OP_GELU)          v = gelu_f(v);
                else if (op==OP_TANHHALF) v = 0.5f*tanhf(v);
                else if (op==OP_SIGMUL)   v = aux[(size_t)m*D_ + n]*sigmoid_f(v);
                else if (op==OP_ADDAUX)   v = v + aux[(size_t)m*D_ + n];
                else if (op==OP_AXPBY)    v = aux[(size_t)m*D_ + n] + 0.3f*v;
                C[(size_t)m*ldc + n] = v;
            }
        }
    }
}

// ---------------------------------------------------------------------------
// Depthwise causal conv, K=8, pad left 7.
// ---------------------------------------------------------------------------
__global__ __launch_bounds__(256) void conv_k(const float* __restrict__ X,
    const float* __restrict__ w, const float* __restrict__ bias, float* __restrict__ out)
{
    int idx = blockIdx.x*256 + threadIdx.x;
    int d = idx & (D_-1);
    int bt = idx >> 8;
    int t = bt & (T_-1);
    float acc = bias[d];
    const float* xp = X + (size_t)bt*D_ + d;
    const float* wp = w + d*8;
    #pragma unroll
    for (int j=0;j<8;++j){
        int tt = t - 7 + j;
        if (tt >= 0) acc += xp[(size_t)(j-7)*D_] * wp[j];
    }
    out[idx] = acc;
}

// ---------------------------------------------------------------------------
// Banded attention: 64-key causal window. QBLK=64 queries/block, 256 threads.
// K/V staged in LDS as bf16 with XOR swizzle (32.5 KB). fp32 math.
// QKVG layout per row (B*T, 1280): [q(256) k(256) v(256) gk(256) gv(256)]
// ---------------------------------------------------------------------------
#define QBLK 64
#define KROWS 127      // QBLK + 63

__global__ __launch_bounds__(256) void attn_k(const float* __restrict__ QKVG, float* __restrict__ MED)
{
    __shared__ unsigned short Ks[KROWS*64];
    __shared__ unsigned short Vs[KROWS*64];
    const int b = blockIdx.z, h = blockIdx.y;
    const int t0 = blockIdx.x * QBLK;
    const int ks0 = t0 - 63;

    for (int i = threadIdx.x; i < KROWS*8; i += 256){
        const int r = i >> 3, c8 = (i & 7)*8;
        const int kg = ks0 + r;
        uint4 pk = {0,0,0,0}, pv = {0,0,0,0};
        if (kg >= 0){
            const float* base = QKVG + ((size_t)(b*T_ + kg))*1280 + 256 + h*HD_ + c8;
            float4 k0 = *(const float4*)base;
            float4 k1 = *(const float4*)(base+4);
            float4 v0 = *(const float4*)(base+256);
            float4 v1 = *(const float4*)(base+260);
            pk = (uint4){ pk2(k0.x,k0.y), pk2(k0.z,k0.w), pk2(k1.x,k1.y), pk2(k1.z,k1.w) };
            pv = (uint4){ pk2(v0.x,v0.y), pk2(v0.z,v0.w), pk2(v1.x,v1.y), pk2(v1.z,v1.w) };
        }
        const int idx = (r*64 + c8) ^ ((r&7)<<3);
        *(uint4*)&Ks[idx] = pk;
        *(uint4*)&Vs[idx] = pv;
    }
    __syncthreads();

    const int qi  = threadIdx.x >> 2;   // 0..63
    const int sub = threadIdx.x & 3;    // 16 dims each
    const int q = t0 + qi;
    const float* qp = QKVG + ((size_t)(b*T_ + q))*1280 + h*HD_ + sub*16;
    float qv[16];
    #pragma unroll
    for (int j=0;j<16;j+=4){
        float4 t = *(const float4*)(qp+j);
        qv[j]=t.x; qv[j+1]=t.y; qv[j+2]=t.z; qv[j+3]=t.w;
    }
    float s[64];
    #pragma unroll
    for (int kk=0;kk<64;++kk){
        const int r = qi + kk;
        const int i0 = (r*64 + sub*16) ^ ((r&7)<<3);
        uint4 u0 = *(const uint4*)&Ks[i0];
        uint4 u1 = *(const uint4*)&Ks[i0 ^ 8];
        float p = 0.f;
        p += qv[0]*bf_lo(u0.x) + qv[1]*bf_hi(u0.x) + qv[2]*bf_lo(u0.y) + qv[3]*bf_hi(u0.y);
        p += qv[4]*bf_lo(u0.z) + qv[5]*bf_hi(u0.z) + qv[6]*bf_lo(u0.w) + qv[7]*bf_hi(u0.w);
        p += qv[8]*bf_lo(u1.x) + qv[9]*bf_hi(u1.x) + qv[10]*bf_lo(u1.y) + qv[11]*bf_hi(u1.y);
        p += qv[12]*bf_lo(u1.z) + qv[13]*bf_hi(u1.z) + qv[14]*bf_lo(u1.w) + qv[15]*bf_hi(u1.w);
        p += __shfl_xor(p,1);
        p += __shfl_xor(p,2);
        s[kk] = (q - 63 + kk >= 0) ? p*0.125f : -1e30f;
    }
    float m = s[0];
    #pragma unroll
    for (int kk=1;kk<64;++kk) m = fmaxf(m, s[kk]);
    float l = 0.f;
    #pragma unroll
    for (int kk=0;kk<64;++kk){ float e = expf(s[kk]-m); s[kk]=e; l+=e; }
    float inv = 1.f/l;
    float o[16];
    #pragma unroll
    for (int j=0;j<16;++j) o[j]=0.f;
    #pragma unroll
    for (int kk=0;kk<64;++kk){
        const float p = s[kk];
        const int r = qi + kk;
        const int i0 = (r*64 + sub*16) ^ ((r&7)<<3);
        uint4 u0 = *(const uint4*)&Vs[i0];
        uint4 u1 = *(const uint4*)&Vs[i0 ^ 8];
        o[0]+=p*bf_lo(u0.x); o[1]+=p*bf_hi(u0.x); o[2]+=p*bf_lo(u0.y); o[3]+=p*bf_hi(u0.y);
        o[4]+=p*bf_lo(u0.z); o[5]+=p*bf_hi(u0.z); o[6]+=p*bf_lo(u0.w); o[7]+=p*bf_hi(u0.w);
        o[8]+=p*bf_lo(u1.x); o[9]+=p*bf_hi(u1.x); o[10]+=p*bf_lo(u1.y); o[11]+=p*bf_hi(u1.y);
        o[12]+=p*bf_lo(u1.z); o[13]+=p*bf_hi(u1.z); o[14]+=p*bf_lo(u1.w); o[15]+=p*bf_hi(u1.w);
    }
    float* op = MED + ((size_t)(b*T_ + q))*D_ + h*HD_ + sub*16;
    #pragma unroll
    for (int j=0;j<16;j+=4){
        float4 t; t.x=o[j]*inv; t.y=o[j+1]*inv; t.z=o[j+2]*inv; t.w=o[j+3]*inv;
        *(float4*)(op+j)=t;
    }
}

// ---------------------------------------------------------------------------
// Chunked parallel scans.
// ---------------------------------------------------------------------------
__global__ __launch_bounds__(256) void scan1_p1(const float* __restrict__ QKVG,
    float* __restrict__ CA, float* __restrict__ CC)
{
    const int d = threadIdx.x, c = blockIdx.x, b = blockIdx.y;
    const float* base = QKVG + ((size_t)(b*T_ + c*LCH))*1280;
    float sgk=0.f, sgkv=0.f;
    for (int t=0;t<LCH;++t){
        float gk = base[(size_t)t*1280 + 768 + d];
        gk = gk > 0.f ? gk + 1.f : expf(gk);
        float gv = base[(size_t)t*1280 + 1024 + d];
        sgk += gk; sgkv += gk*gv;
    }
    CA[((size_t)b*NC_ + c)*D_ + d] = sgk;
    CC[((size_t)b*NC_ + c)*D_ + d] = sgkv;
}

__global__ void scan1_p2(float* __restrict__ CA, float* __restrict__ CC)
{
    int idx = blockIdx.x*256 + threadIdx.x;
    int d = idx & (D_-1), b = idx >> 8;
    float sa=0.f, sc=0.f;
    for (int c=0;c<NC_;++c){
        size_t o = ((size_t)b*NC_ + c)*D_ + d;
        float a = CA[o], cc = CC[o];
        CA[o] = sa; CC[o] = sc;
        sa += a; sc += cc;
    }
}

__global__ __launch_bounds__(256) void scan1_p3(const float* __restrict__ QKVG,
    const float* __restrict__ CA, const float* __restrict__ CC, float* __restrict__ CONC)
{
    const int d = threadIdx.x, c = blockIdx.x, b = blockIdx.y;
    float sgk  = CA[((size_t)b*NC_ + c)*D_ + d];
    float sgkv = CC[((size_t)b*NC_ + c)*D_ + d];
    const float* base = QKVG + ((size_t)(b*T_ + c*LCH))*1280;
    float* out = CONC + ((size_t)(b*T_ + c*LCH))*D_ + d;
    for (int t=0;t<LCH;++t){
        float gk = base[(size_t)t*1280 + 768 + d];
        gk = gk > 0.f ? gk + 1.f : expf(gk);
        float gv = base[(size_t)t*1280 + 1024 + d];
        sgk += gk; sgkv += gk*gv;
        out[(size_t)t*D_] = sgkv / (sgk + 1e-5f);
    }
}

__global__ __launch_bounds__(256) void ema_p1(const float* __restrict__ X,
    float* __restrict__ CARRY, float alpha)
{
    const int d = threadIdx.x, c = blockIdx.x, b = blockIdx.y;
    const float* xp = X + ((size_t)(b*T_ + c*LCH))*D_ + d;
    float g = 0.f;
    for (int t=0;t<LCH;++t) g = 0.9f*g + alpha*xp[(size_t)t*D_];
    CARRY[((size_t)b*NC_ + c)*D_ + d] = g;
}

__global__ void ema_p2(float* __restrict__ CARRY, float* __restrict__ traj)
{
    int idx = blockIdx.x*256 + threadIdx.x;
    int d = idx & (D_-1), b = idx >> 8;
    const float dL = powf(0.9f, (float)LCH);
    float run = 0.f;
    for (int c=0;c<NC_;++c){
        size_t o = ((size_t)b*NC_ + c)*D_ + d;
        float loc = CARRY[o];
        CARRY[o] = run;
        run = loc + dL*run;
    }
    if (traj) traj[b*D_ + d] = run;
}

__global__ __launch_bounds__(256) void ema_p3(const float* __restrict__ X,
    const float* __restrict__ CARRY, float* __restrict__ OUT, float alpha)
{
    const int d = threadIdx.x, c = blockIdx.x, b = blockIdx.y;
    float g = CARRY[((size_t)b*NC_ + c)*D_ + d];
    const float* xp = X + ((size_t)(b*T_ + c*LCH))*D_ + d;
    float* op = OUT + ((size_t)(b*T_ + c*LCH))*D_ + d;
    for (int t=0;t<LCH;++t){
        g = 0.9f*g + alpha*xp[(size_t)t*D_];
        op[(size_t)t*D_] = g;
    }
}

__global__ __launch_bounds__(256) void ema_p3_state(const float* __restrict__ X,
    const float* __restrict__ CARRY, const float* __restrict__ SEQ, float* __restrict__ OUT)
{
    const int d = threadIdx.x, c = blockIdx.x, b = blockIdx.y;
    float a = CARRY[((size_t)b*NC_ + c)*D_ + d];
    const float ss = SEQ[b*D_ + d];
    float dp = powf(0.9f, (float)(c*LCH + 1));
    const float* xp = X + ((size_t)(b*T_ + c*LCH))*D_ + d;
    float* op = OUT + ((size_t)(b*T_ + c*LCH))*D_ + d;
    for (int t=0;t<LCH;++t){
        a = 0.9f*a + xp[(size_t)t*D_];
        op[(size_t)t*D_] = fmaf(ss, dp, a);
        dp *= 0.9f;
    }
}

// ---------------------------------------------------------------------------
// LayerNorms
// ---------------------------------------------------------------------------
__global__ __launch_bounds__(256) void ln_k(const float* __restrict__ in,
    const float* __restrict__ g, const float* __restrict__ b, float* __restrict__ out)
{
    int row  = blockIdx.x*4 + (threadIdx.x>>6);
    int lane = threadIdx.x & 63;
    const float* ip = in + (size_t)row*D_ + lane*4;
    float4 x = *(const float4*)ip;
    float s  = x.x+x.y+x.z+x.w;
    float s2 = x.x*x.x + x.y*x.y + x.z*x.z + x.w*x.w;
    #pragma unroll
    for (int o=1;o<64;o<<=1){ s += __shfl_xor(s,o); s2 += __shfl_xor(s2,o); }
    float mean = s * (1.f/256.f);
    float var  = s2 * (1.f/256.f) - mean*mean;
    float rs = rsqrtf(var + 1e-5f);
    int db = lane*4;
    float4 r;
    r.x=(x.x-mean)*rs*g[db+0]+b[db+0];
    r.y=(x.y-mean)*rs*g[db+1]+b[db+1];
    r.z=(x.z-mean)*rs*g[db+2]+b[db+2];
    r.w=(x.w-mean)*rs*g[db+3]+b[db+3];
    *(float4*)(out + (size_t)row*D_ + db) = r;
}

__global__ __launch_bounds__(256) void ln3_k(const float* __restrict__ in,
    const float* __restrict__ g3, const float* __restrict__ b3, float* __restrict__ states,
    const float* __restrict__ g4, const float* __restrict__ b4, float* __restrict__ fsout)
{
    int row  = blockIdx.x*4 + (threadIdx.x>>6);
    int lane = threadIdx.x & 63;
    const float* ip = in + (size_t)row*D_ + lane*4;
    float4 x = *(const float4*)ip;
    float s  = x.x+x.y+x.z+x.w;
    float s2 = x.x*x.x + x.y*x.y + x.z*x.z + x.w*x.w;
    #pragma unroll
    for (int o=1;o<64;o<<=1){ s += __shfl_xor(s,o); s2 += __shfl_xor(s2,o); }
    float mean = s * (1.f/256.f);
    float var  = s2 * (1.f/256.f) - mean*mean;
    float rs = rsqrtf(var + 1e-5f);
    int db = lane*4;
    float4 st;
    st.x=(x.x-mean)*rs*g3[db+0]+b3[db+0];
    st.y=(x.y-mean)*rs*g3[db+1]+b3[db+1];
    st.z=(x.z-mean)*rs*g3[db+2]+b3[db+2];
    st.w=(x.w-mean)*rs*g3[db+3]+b3[db+3];
    *(float4*)(states + (size_t)row*D_ + db) = st;

    if ((row & (T_-1)) == T_-1){
        float u  = st.x+st.y+st.z+st.w;
        float u2 = st.x*st.x + st.y*st.y + st.z*st.z + st.w*st.w;
        #pragma unroll
        for (int o=1;o<64;o<<=1){ u += __shfl_xor(u,o); u2 += __shfl_xor(u2,o); }
        float m2 = u * (1.f/256.f);
        float v2 = u2 * (1.f/256.f) - m2*m2;
        float r2 = rsqrtf(v2 + 1e-5f);
        float4 fs;
        fs.x=(st.x-m2)*r2*g4[db+0]+b4[db+0];
        fs.y=(st.y-m2)*r2*g4[db+1]+b4[db+1];
        fs.z=(st.z-m2)*r2*g4[db+2]+b4[db+2];
        fs.w=(st.w-m2)*r2*g4[db+3]+b4[db+3];
        *(float4*)(fsout + (size_t)(row>>11)*D_ + db) = fs;
    }
}

// ---------------------------------------------------------------------------
extern "C" void kernel_launch(void* const* d_in, const int* in_sizes, int n_in,
                              void* d_out, int out_size, void* d_ws, size_t ws_size,
                              hipStream_t stream)
{
    const float* X     = (const float*)d_in[0];
    const float* SEQ   = (const float*)d_in[1];
    const float* conv_w= (const float*)d_in[3];
    const float* conv_b= (const float*)d_in[4];
    const float* qkv_w = (const float*)d_in[5];
    const float* qkv_b = (const float*)d_in[6];
    const float* mo_w  = (const float*)d_in[7];
    const float* mo_b  = (const float*)d_in[8];
    const float* fg_w  = (const float*)d_in[9];
    const float* fg_b  = (const float*)d_in[10];
    const float* gkv_w = (const float*)d_in[11];
    const float* gkv_b = (const float*)d_in[12];
    const float* go_w  = (const float*)d_in[13];
    const float* go_b  = (const float*)d_in[14];
    const float* comb_w= (const float*)d_in[15];
    const float* comb_b= (const float*)d_in[16];
    const float* ffn1_w= (const float*)d_in[17];
    const float* ffn1_b= (const float*)d_in[18];
    const float* ffn2_w= (const float*)d_in[19];
    const float* ffn2_b= (const float*)d_in[20];
    const float* tr1_w = (const float*)d_in[21];
    const float* tr1_b = (const float*)d_in[22];
    const float* tr2_w = (const float*)d_in[23];
    const float* tr2_b = (const float*)d_in[24];
    const float* p2s_w = (const float*)d_in[25];
    const float* p2s_b = (const float*)d_in[26];
    const float* s2p_w = (const float*)d_in[27];
    const float* s2p_b = (const float*)d_in[28];
    const float* ln1_g = (const float*)d_in[29];
    const float* ln1_b = (const float*)d_in[30];
    const float* ln2_g = (const float*)d_in[31];
    const float* ln2_b = (const float*)d_in[32];
    const float* ln3_g = (const float*)d_in[33];
    const float* ln3_b = (const float*)d_in[34];
    const float* ln4_g = (const float*)d_in[35];
    const float* ln4_b = (const float*)d_in[36];

    float* ws   = (float*)d_ws;
    float* QKVG = ws;                          // M*1280  (reused later as H2: M*1024)
    float* H1   = QKVG + (size_t)M_*1280;      // M*512   (aliased as scan-carry space)
    float* BUF2 = H1   + (size_t)M_*512;
    float* BUF3 = BUF2 + (size_t)M_*256;
    float* BUF4 = BUF3 + (size_t)M_*256;
    float* BUF5 = BUF4 + (size_t)M_*256;
    float* BUF6 = BUF5 + (size_t)M_*256;
    float* H2   = QKVG;

    float* CAR0 = H1;
    float* CAR1 = H1 + (size_t)B_*NC_*D_;

    float* out_pr = (float*)d_out;
    float* out_fs = out_pr + (size_t)M_*256;
    float* out_tj = out_fs + B_*256;

    const dim3 blk256(256);
    const dim3 scan_grid(NC_, B_);
    const int NR = M_/64;   // 128 row tiles

    // 1. qkv projection -> QKVG[:, 0:768)
    gemm_k<<<dim3(NR*12), blk256, 0, stream>>>(
        X, qkv_w, 256, 256,  nullptr,nullptr,0,0,  nullptr,nullptr,0,0,
        qkv_b, nullptr, QKVG, 1280, OP_NONE, 12);
    // 2. gkv projection -> QKVG[:, 768:1280)
    gemm_k<<<dim3(NR*8), blk256, 0, stream>>>(
        X, gkv_w, 256, 256,  nullptr,nullptr,0,0,  nullptr,nullptr,0,0,
        gkv_b, nullptr, QKVG+768, 1280, OP_NONE, 8);
    // 3. local_history (depthwise conv) -> BUF2
    conv_k<<<dim3(M_*D_/256), blk256, 0, stream>>>(X, conv_w, conv_b, BUF2);
    // 4. banded attention -> BUF3 (MED, pre-mo)
    attn_k<<<dim3(T_/QBLK, H_, B_), blk256, 0, stream>>>(QKVG, BUF3);
    // 5. mo projection -> BUF4
    gemm_k<<<dim3(NR*4), blk256, 0, stream>>>(
        BUF3, mo_w, 256, 256,  nullptr,nullptr,0,0,  nullptr,nullptr,0,0,
        mo_b, nullptr, BUF4, 256, OP_NONE, 4);
    // 6. concepts scan (chunked) -> BUF5
    scan1_p1<<<scan_grid, blk256, 0, stream>>>(QKVG, CAR0, CAR1);
    scan1_p2<<<dim3(4), blk256, 0, stream>>>(CAR0, CAR1);
    scan1_p3<<<scan_grid, blk256, 0, stream>>>(QKVG, CAR0, CAR1, BUF5);
    // 7. global_out -> BUF6
    gemm_k<<<dim3(NR*4), blk256, 0, stream>>>(
        BUF5, go_w, 256, 256,  nullptr,nullptr,0,0,  nullptr,nullptr,0,0,
        go_b, nullptr, BUF6, 256, OP_NONE, 4);
    // 8. medium_out = MED2 * sigmoid([X,MED2]@fg^T + b) -> BUF3
    gemm_k<<<dim3(NR*4), blk256, 0, stream>>>(
        X, fg_w, 512, 256,  BUF4, fg_w+256, 512, 256,  nullptr,nullptr,0,0,
        fg_b, BUF4, BUF3, 256, OP_SIGMUL, 4);
    // 9. pre_ln1 = X + [LH,MOUT,GOUT]@comb^T + b -> BUF4
    gemm_k<<<dim3(NR*4), blk256, 0, stream>>>(
        BUF2, comb_w, 768, 256,  BUF3, comb_w+256, 768, 256,  BUF6, comb_w+512, 768, 256,
        comb_b, X, BUF4, 256, OP_ADDAUX, 4);
    // 10. pr = LN1 -> BUF5
    ln_k<<<dim3(M_/4), blk256, 0, stream>>>(BUF4, ln1_g, ln1_b, BUF5);
    // 11. global_summary EMA -> BUF6, final_traj -> out
    ema_p1<<<scan_grid, blk256, 0, stream>>>(BUF5, CAR0, 0.1f);
    ema_p2<<<dim3(4), blk256, 0, stream>>>(CAR0, out_tj);
    ema_p3<<<scan_grid, blk256, 0, stream>>>(BUF5, CAR0, BUF6, 0.1f);
    // 12. cs1 = pr + 0.3*(pr@p2s^T + b) -> BUF2
    gemm_k<<<dim3(NR*4), blk256, 0, stream>>>(
        BUF5, p2s_w, 256, 256,  nullptr,nullptr,0,0,  nullptr,nullptr,0,0,
        p2s_b, BUF5, BUF2, 256, OP_AXPBY, 4);
    // 13. H1 = gelu(cs1@tr1a + gsum@tr1b + b)
    gemm_k<<<dim3(NR*8), blk256, 0, stream>>>(
        BUF2, tr1_w, 512, 256,  BUF6, tr1_w+256, 512, 256,  nullptr,nullptr,0,0,
        tr1_b, nullptr, H1, 512, OP_GELU, 8);
    // 14. scaled = 0.5*tanh(H1@tr2^T + b) -> BUF3
    gemm_k<<<dim3(NR*4), blk256, 0, stream>>>(
        H1, tr2_w, 512, 512,  nullptr,nullptr,0,0,  nullptr,nullptr,0,0,
        tr2_b, nullptr, BUF3, 256, OP_TANHHALF, 4);
    // 15. state EMA + decayed initial -> BUF4 (pre_ln3)
    ema_p1<<<scan_grid, blk256, 0, stream>>>(BUF3, CAR0, 1.0f);
    ema_p2<<<dim3(4), blk256, 0, stream>>>(CAR0, nullptr);
    ema_p3_state<<<scan_grid, blk256, 0, stream>>>(BUF3, CAR0, SEQ, BUF4);
    // 16. states = LN3 -> BUF6; final_state = LN4(states[-1]) -> out
    ln3_k<<<dim3(M_/4), blk256, 0, stream>>>(BUF4, ln3_g, ln3_b, BUF6, ln4_g, ln4_b, out_fs);
    // 17. ffn_in = pr + 0.3*(states@s2p^T + b) -> BUF2
    gemm_k<<<dim3(NR*4), blk256, 0, stream>>>(
        BUF6, s2p_w, 256, 256,  nullptr,nullptr,0,0,  nullptr,nullptr,0,0,
        s2p_b, BUF5, BUF2, 256, OP_AXPBY, 4);
    // 18. H2 = gelu(ffn_in@ffn1^T + b)
    gemm_k<<<dim3(NR*16), blk256, 0, stream>>>(
        BUF2, ffn1_w, 256, 256,  nullptr,nullptr,0,0,  nullptr,nullptr,0,0,
        ffn1_b, nullptr, H2, 1024, OP_GELU, 16);
    // 19. pre_ln2 = pr + H2@ffn2^T + b -> BUF3
    gemm_k<<<dim3(NR*4), blk256, 0, stream>>>(
        H2, ffn2_w, 1024, 1024,  nullptr,nullptr,0,0,  nullptr,nullptr,0,0,
        ffn2_b, BUF5, BUF3, 256, OP_ADDAUX, 4);
    // 20. pr_out = LN2 -> d_out
    ln_k<<<dim3(M_/4), blk256, 0, stream>>>(BUF3, ln2_g, ln2_b, out_pr);
}

// Round 4
// 323.638 us; speedup vs baseline: 3.4361x; 1.1636x over previous
//
#include <hip/hip_runtime.h>
#include <hip/hip_bf16.h>
#include <math.h>

#define D_  256
#define T_  2048
#define B_  4
#define M_  (B_*T_)
#define H_  4
#define HD_ 64

#define NC_ 64          // scan chunks
#define LCH (T_/NC_)    // 32 steps per chunk

enum { OP_NONE=0, OP_SIGMUL=1, OP_ADDAUX=2, OP_AXPBY=3, OP_GELU=4, OP_TANHHALF=5 };

typedef short short8 __attribute__((ext_vector_type(8)));
typedef float f32x4  __attribute__((ext_vector_type(4)));

__device__ __forceinline__ float gelu_f(float x){ return 0.5f*x*(1.0f+erff(x*0.70710678118654752f)); }
__device__ __forceinline__ float sigmoid_f(float x){ return 1.0f/(1.0f+expf(-x)); }

// pack 2 fp32 -> 2 bf16 (RNE) in one uint (low ushort = a, high = b)
__device__ __forceinline__ unsigned pk2(float a, float b){
    __hip_bfloat162 h = __float22bfloat162_rn(make_float2(a,b));
    union { __hip_bfloat162 h; unsigned u; } c; c.h = h; return c.u;
}

// ---------------------------------------------------------------------------
// bf16 MFMA GEMM: C[m,n] = sum_p A_p[m,:] . W_p[n,:] + bias[n], epilogue op.
// Block tile 64x64, BK=64, 4 waves (2x2), mfma_f32_16x16x32_bf16.
// Optional vt side-output: for n in [512,768) also writes V^T[b][h][d][t].
// ---------------------------------------------------------------------------
__global__ __launch_bounds__(256) void gemm_k(
    const float* __restrict__ A0, const float* __restrict__ W0, int ldw0, int K0,
    const float* __restrict__ A1, const float* __restrict__ W1, int ldw1, int K1,
    const float* __restrict__ A2, const float* __restrict__ W2, int ldw2, int K2,
    const float* __restrict__ bias, const float* __restrict__ aux,
    float* __restrict__ C, int ldc, int op, int ncol, float* __restrict__ vt)
{
    __shared__ unsigned short As[64*64];
    __shared__ unsigned short Ws[64*64];

    const int q8   = gridDim.x >> 3;
    const int lid  = (blockIdx.x & 7)*q8 + (blockIdx.x >> 3);
    const int brow = lid / ncol;
    const int bcol = lid - brow*ncol;
    const int row0 = brow*64, col0 = bcol*64;

    const int tid  = threadIdx.x;
    const int lane = tid & 63, wid = tid >> 6;
    const int wm = (wid >> 1)*32, wn = (wid & 1)*32;
    const int l15 = lane & 15, l4 = lane >> 4;

    f32x4 acc[2][2];
    #pragma unroll
    for (int i=0;i<2;++i)
        #pragma unroll
        for (int j=0;j<2;++j) acc[i][j] = (f32x4){0.f,0.f,0.f,0.f};

    const float* Aps[3]={A0,A1,A2};
    const float* Wps[3]={W0,W1,W2};
    const int ldws[3]={ldw0,ldw1,ldw2};
    const int Kks[3]={K0,K1,K2};

    const int srow = tid >> 3;
    const int sc8  = (tid & 7) * 8;

    for (int p=0;p<3;++p){
        const float* A = Aps[p];
        if (!A) break;
        const float* W = Wps[p];
        const int K = Kks[p];
        const int ldw = ldws[p];
        for (int kb=0; kb<K; kb+=64){
            __syncthreads();
            #pragma unroll
            for (int rep=0;rep<2;++rep){
                const int row = srow + rep*32;
                const float* ga = A + (size_t)(row0+row)*K + kb + sc8;
                float4 a0 = *(const float4*)ga;
                float4 a1 = *(const float4*)(ga+4);
                uint4 pa = { pk2(a0.x,a0.y), pk2(a0.z,a0.w), pk2(a1.x,a1.y), pk2(a1.z,a1.w) };
                const int ia = (row*64 + sc8) ^ ((row&7)<<3);
                *(uint4*)&As[ia] = pa;
                const float* gw = W + (size_t)(col0+row)*ldw + kb + sc8;
                float4 w0 = *(const float4*)gw;
                float4 w1 = *(const float4*)(gw+4);
                uint4 pw = { pk2(w0.x,w0.y), pk2(w0.z,w0.w), pk2(w1.x,w1.y), pk2(w1.z,w1.w) };
                *(uint4*)&Ws[ia] = pw;
            }
            __syncthreads();
            #pragma unroll
            for (int ks=0;ks<2;++ks){
                const int koff = ks*32 + l4*8;
                short8 af[2], bf[2];
                #pragma unroll
                for (int f=0;f<2;++f){
                    const int ar = wm + f*16 + l15;
                    af[f] = *(const short8*)&As[(ar*64 + koff) ^ ((ar&7)<<3)];
                    const int brn = wn + f*16 + l15;
                    bf[f] = *(const short8*)&Ws[(brn*64 + koff) ^ ((brn&7)<<3)];
                }
                #pragma unroll
                for (int fm=0;fm<2;++fm)
                    #pragma unroll
                    for (int fn=0;fn<2;++fn)
                        acc[fm][fn] = __builtin_amdgcn_mfma_f32_16x16x32_bf16(
                            af[fm], bf[fn], acc[fm][fn], 0, 0, 0);
            }
        }
    }

    #pragma unroll
    for (int fn=0;fn<2;++fn){
        const int n = col0 + wn + fn*16 + l15;
        const float bv = bias[n];
        const bool vwr = (vt != nullptr) && (n >= 512) && (n < 768);
        #pragma unroll
        for (int fm=0;fm<2;++fm){
            #pragma unroll
            for (int j=0;j<4;++j){
                const int m = row0 + wm + fm*16 + l4*4 + j;
                float v = acc[fm][fn][j] + bv;
                if (op==OP_GELU)          v = gelu_f(v);
                else if (op==OP_TANHHALF) v = 0.5f*tanhf(v);
                else if (op==OP_SIGMUL)   v = aux[(size_t)m*D_ + n]*sigmoid_f(v);
                else if (op==OP_ADDAUX)   v = v + aux[(size_t)m*D_ + n];
                else if (op==OP_AXPBY)    v = aux[(size_t)m*D_ + n] + 0.3f*v;
                C[(size_t)m*ldc + n] = v;
                if (vwr){
                    const int hh = (n-512)>>6, dd = (n-512)&63;
                    const int bb = m >> 11, tt = m & (T_-1);
                    vt[(((size_t)(bb*H_ + hh))*64 + dd)*T_ + tt] = v;
                }
            }
        }
    }
}

// ---------------------------------------------------------------------------
// Depthwise causal conv, K=8, pad left 7.
// ---------------------------------------------------------------------------
__global__ __launch_bounds__(256) void conv_k(const float* __restrict__ X,
    const float* __restrict__ w, const float* __restrict__ bias, float* __restrict__ out)
{
    int idx = blockIdx.x*256 + threadIdx.x;
    int d = idx & (D_-1);
    int bt = idx >> 8;
    int t = bt & (T_-1);
    float acc = bias[d];
    const float* xp = X + (size_t)bt*D_ + d;
    const float* wp = w + d*8;
    #pragma unroll
    for (int j=0;j<8;++j){
        int tt = t - 7 + j;
        if (tt >= 0) acc += xp[(size_t)(j-7)*D_] * wp[j];
    }
    out[idx] = acc;
}

// ---------------------------------------------------------------------------
// MFMA banded attention. Per block: (b, h, 64-query tile), 4 waves.
// S^T = K.Q^T (lane holds P column for one query) -> in-register softmax ->
// in-register P->A-fragment permute -> O = P^T.V via VT tile in LDS.
// QKVG layout per row (B*T,1280): [q k v gk gv]; VT: [b][h][d][t] fp32.
// ---------------------------------------------------------------------------
__global__ __launch_bounds__(256) void attn_k(const float* __restrict__ QKVG,
    const float* __restrict__ VT, float* __restrict__ MED)
{
    __shared__ unsigned short Kl[128*64];
    __shared__ unsigned short Ql[64*64];
    __shared__ unsigned short Vl[64*128];
    const int b = blockIdx.z, h = blockIdx.y;
    const int t0 = blockIdx.x * 64;
    const int kb0 = t0 - 64;
    const int tid = threadIdx.x;

    {   // stage K (128 key rows x 64 dims) and Q (64 rows)
        const int r0 = tid >> 3, c8 = (tid & 7) * 8;
        #pragma unroll
        for (int rep=0;rep<4;++rep){
            const int r = r0 + rep*32;
            const int kg = kb0 + r;
            uint4 pk = {0,0,0,0};
            if (kg >= 0){
                const float* gp = QKVG + ((size_t)(b*T_ + kg))*1280 + 256 + h*HD_ + c8;
                float4 x0 = *(const float4*)gp, x1 = *(const float4*)(gp+4);
                pk = (uint4){pk2(x0.x,x0.y),pk2(x0.z,x0.w),pk2(x1.x,x1.y),pk2(x1.z,x1.w)};
            }
            *(uint4*)&Kl[(r*64 + c8) ^ ((r&7)<<3)] = pk;
        }
        #pragma unroll
        for (int rep=0;rep<2;++rep){
            const int r = r0 + rep*32;
            const float* gp = QKVG + ((size_t)(b*T_ + t0 + r))*1280 + h*HD_ + c8;
            float4 x0 = *(const float4*)gp, x1 = *(const float4*)(gp+4);
            uint4 pq = (uint4){pk2(x0.x,x0.y),pk2(x0.z,x0.w),pk2(x1.x,x1.y),pk2(x1.z,x1.w)};
            *(uint4*)&Ql[(r*64 + c8) ^ ((r&7)<<3)] = pq;
        }
    }
    {   // stage VT (64 dims x 128 keys)
        const int d0 = tid >> 4, c8 = (tid & 15) * 8;
        #pragma unroll
        for (int rep=0;rep<4;++rep){
            const int d = d0 + rep*16;
            uint4 pv = {0,0,0,0};
            if (kb0 + c8 >= 0){
                const float* gp = VT + ((size_t)(b*H_ + h)*64 + d)*T_ + kb0 + c8;
                float4 x0 = *(const float4*)gp, x1 = *(const float4*)(gp+4);
                pv = (uint4){pk2(x0.x,x0.y),pk2(x0.z,x0.w),pk2(x1.x,x1.y),pk2(x1.z,x1.w)};
            }
            *(uint4*)&Vl[(d*128 + c8) ^ ((d&7)<<3)] = pv;
        }
    }
    __syncthreads();

    const int lane = tid & 63, w = tid >> 6;
    const int l15 = lane & 15, l4 = lane >> 4;

    short8 bq[2];
    {
        const int qr = w*16 + l15;
        bq[0] = *(const short8*)&Ql[(qr*64 +      l4*8) ^ ((qr&7)<<3)];
        bq[1] = *(const short8*)&Ql[(qr*64 + 32 + l4*8) ^ ((qr&7)<<3)];
    }

    // S^T: rows = keys (128), cols = queries (16 per wave)
    f32x4 s[8];
    #pragma unroll
    for (int kf=0;kf<8;++kf){
        const int kr = kf*16 + l15;
        short8 a0 = *(const short8*)&Kl[(kr*64 +      l4*8) ^ ((kr&7)<<3)];
        short8 a1 = *(const short8*)&Kl[(kr*64 + 32 + l4*8) ^ ((kr&7)<<3)];
        f32x4 acc = (f32x4){0.f,0.f,0.f,0.f};
        acc = __builtin_amdgcn_mfma_f32_16x16x32_bf16(a0, bq[0], acc, 0,0,0);
        acc = __builtin_amdgcn_mfma_f32_16x16x32_bf16(a1, bq[1], acc, 0,0,0);
        s[kf] = acc;
    }

    // mask + softmax (query = l15, keys spread over l4 groups and regs)
    const int qg = t0 + w*16 + l15;
    float m = -1e30f;
    #pragma unroll
    for (int kf=0;kf<8;++kf){
        #pragma unroll
        for (int j=0;j<4;++j){
            const int kg = kb0 + kf*16 + l4*4 + j;
            const int diff = qg - kg;
            const float v = (kg >= 0 && diff >= 0 && diff < 64) ? s[kf][j]*0.125f : -1e30f;
            s[kf][j] = v;
            m = fmaxf(m, v);
        }
    }
    m = fmaxf(m, __shfl_xor(m,16));
    m = fmaxf(m, __shfl_xor(m,32));
    float lsum = 0.f;
    unsigned lo[8], hi[8];
    #pragma unroll
    for (int kf=0;kf<8;++kf){
        const float p0 = expf(s[kf][0]-m), p1 = expf(s[kf][1]-m);
        const float p2 = expf(s[kf][2]-m), p3 = expf(s[kf][3]-m);
        lsum += (p0+p1)+(p2+p3);
        lo[kf] = pk2(p0,p1);
        hi[kf] = pk2(p2,p3);
    }
    lsum += __shfl_xor(lsum,16);
    lsum += __shfl_xor(lsum,32);
    const float inv = 1.f/lsum;

    // PV: A = P^T (built via static shuffles), B = VT fragments from LDS
    f32x4 o[4];
    #pragma unroll
    for (int df=0;df<4;++df) o[df] = (f32x4){0.f,0.f,0.f,0.f};
    const int baseLane = l15 + ((l4&1)<<5);
    const bool hiHalf = (l4>>1) != 0;
    #pragma unroll
    for (int kb=0;kb<4;++kb){
        const int x0 = __shfl((int)lo[2*kb],   baseLane);
        const int x1 = __shfl((int)hi[2*kb],   baseLane);
        const int x2 = __shfl((int)lo[2*kb],   baseLane+16);
        const int x3 = __shfl((int)hi[2*kb],   baseLane+16);
        const int y0 = __shfl((int)lo[2*kb+1], baseLane);
        const int y1 = __shfl((int)hi[2*kb+1], baseLane);
        const int y2 = __shfl((int)lo[2*kb+1], baseLane+16);
        const int y3 = __shfl((int)hi[2*kb+1], baseLane+16);
        int4 afi;
        afi.x = hiHalf ? y0 : x0;
        afi.y = hiHalf ? y1 : x1;
        afi.z = hiHalf ? y2 : x2;
        afi.w = hiHalf ? y3 : x3;
        union { int4 i; short8 s; } cv; cv.i = afi;
        #pragma unroll
        for (int df=0;df<4;++df){
            const int vr = df*16 + l15;
            short8 bv = *(const short8*)&Vl[(vr*128 + kb*32 + l4*8) ^ ((vr&7)<<3)];
            o[df] = __builtin_amdgcn_mfma_f32_16x16x32_bf16(cv.s, bv, o[df], 0,0,0);
        }
    }

    // O: row = query (l4*4+j), col = dim (df*16 + l15)
    #pragma unroll
    for (int j=0;j<4;++j){
        const float invj = __shfl(inv, l4*4 + j);
        const int mrow = b*T_ + t0 + w*16 + l4*4 + j;
        float* op = MED + (size_t)mrow*D_ + h*HD_ + l15;
        #pragma unroll
        for (int df=0;df<4;++df)
            op[df*16] = o[df][j] * invj;
    }
}

// ---------------------------------------------------------------------------
// Chunked parallel scans.
// ---------------------------------------------------------------------------
__global__ __launch_bounds__(256) void scan1_p1(const float* __restrict__ QKVG,
    float* __restrict__ CA, float* __restrict__ CC)
{
    const int d = threadIdx.x, c = blockIdx.x, b = blockIdx.y;
    const float* base = QKVG + ((size_t)(b*T_ + c*LCH))*1280;
    float sgk=0.f, sgkv=0.f;
    for (int t=0;t<LCH;++t){
        float gk = base[(size_t)t*1280 + 768 + d];
        gk = gk > 0.f ? gk + 1.f : expf(gk);
        float gv = base[(size_t)t*1280 + 1024 + d];
        sgk += gk; sgkv += gk*gv;
    }
    CA[((size_t)b*NC_ + c)*D_ + d] = sgk;
    CC[((size_t)b*NC_ + c)*D_ + d] = sgkv;
}

__global__ void scan1_p2(float* __restrict__ CA, float* __restrict__ CC)
{
    int idx = blockIdx.x*256 + threadIdx.x;
    int d = idx & (D_-1), b = idx >> 8;
    float sa=0.f, sc=0.f;
    for (int c=0;c<NC_;++c){
        size_t o = ((size_t)b*NC_ + c)*D_ + d;
        float a = CA[o], cc = CC[o];
        CA[o] = sa; CC[o] = sc;
        sa += a; sc += cc;
    }
}

__global__ __launch_bounds__(256) void scan1_p3(const float* __restrict__ QKVG,
    const float* __restrict__ CA, const float* __restrict__ CC, float* __restrict__ CONC)
{
    const int d = threadIdx.x, c = blockIdx.x, b = blockIdx.y;
    float sgk  = CA[((size_t)b*NC_ + c)*D_ + d];
    float sgkv = CC[((size_t)b*NC_ + c)*D_ + d];
    const float* base = QKVG + ((size_t)(b*T_ + c*LCH))*1280;
    float* out = CONC + ((size_t)(b*T_ + c*LCH))*D_ + d;
    for (int t=0;t<LCH;++t){
        float gk = base[(size_t)t*1280 + 768 + d];
        gk = gk > 0.f ? gk + 1.f : expf(gk);
        float gv = base[(size_t)t*1280 + 1024 + d];
        sgk += gk; sgkv += gk*gv;
        out[(size_t)t*D_] = sgkv / (sgk + 1e-5f);
    }
}

__global__ __launch_bounds__(256) void ema_p1(const float* __restrict__ X,
    float* __restrict__ CARRY, float alpha)
{
    const int d = threadIdx.x, c = blockIdx.x, b = blockIdx.y;
    const float* xp = X + ((size_t)(b*T_ + c*LCH))*D_ + d;
    float g = 0.f;
    for (int t=0;t<LCH;++t) g = 0.9f*g + alpha*xp[(size_t)t*D_];
    CARRY[((size_t)b*NC_ + c)*D_ + d] = g;
}

__global__ void ema_p2(float* __restrict__ CARRY, float* __restrict__ traj)
{
    int idx = blockIdx.x*256 + threadIdx.x;
    int d = idx & (D_-1), b = idx >> 8;
    const float dL = powf(0.9f, (float)LCH);
    float run = 0.f;
    for (int c=0;c<NC_;++c){
        size_t o = ((size_t)b*NC_ + c)*D_ + d;
        float loc = CARRY[o];
        CARRY[o] = run;
        run = loc + dL*run;
    }
    if (traj) traj[b*D_ + d] = run;
}

__global__ __launch_bounds__(256) void ema_p3(const float* __restrict__ X,
    const float* __restrict__ CARRY, float* __restrict__ OUT, float alpha)
{
    const int d = threadIdx.x, c = blockIdx.x, b = blockIdx.y;
    float g = CARRY[((size_t)b*NC_ + c)*D_ + d];
    const float* xp = X + ((size_t)(b*T_ + c*LCH))*D_ + d;
    float* op = OUT + ((size_t)(b*T_ + c*LCH))*D_ + d;
    for (int t=0;t<LCH;++t){
        g = 0.9f*g + alpha*xp[(size_t)t*D_];
        op[(size_t)t*D_] = g;
    }
}

__global__ __launch_bounds__(256) void ema_p3_state(const float* __restrict__ X,
    const float* __restrict__ CARRY, const float* __restrict__ SEQ, float* __restrict__ OUT)
{
    const int d = threadIdx.x, c = blockIdx.x, b = blockIdx.y;
    float a = CARRY[((size_t)b*NC_ + c)*D_ + d];
    const float ss = SEQ[b*D_ + d];
    float dp = powf(0.9f, (float)(c*LCH + 1));
    const float* xp = X + ((size_t)(b*T_ + c*LCH))*D_ + d;
    float* op = OUT + ((size_t)(b*T_ + c*LCH))*D_ + d;
    for (int t=0;t<LCH;++t){
        a = 0.9f*a + xp[(size_t)t*D_];
        op[(size_t)t*D_] = fmaf(ss, dp, a);
        dp *= 0.9f;
    }
}

// ---------------------------------------------------------------------------
// LayerNorms
// ---------------------------------------------------------------------------
__global__ __launch_bounds__(256) void ln_k(const float* __restrict__ in,
    const float* __restrict__ g, const float* __restrict__ b, float* __restrict__ out)
{
    int row  = blockIdx.x*4 + (threadIdx.x>>6);
    int lane = threadIdx.x & 63;
    const float* ip = in + (size_t)row*D_ + lane*4;
    float4 x = *(const float4*)ip;
    float s  = x.x+x.y+x.z+x.w;
    float s2 = x.x*x.x + x.y*x.y + x.z*x.z + x.w*x.w;
    #pragma unroll
    for (int o=1;o<64;o<<=1){ s += __shfl_xor(s,o); s2 += __shfl_xor(s2,o); }
    float mean = s * (1.f/256.f);
    float var  = s2 * (1.f/256.f) - mean*mean;
    float rs = rsqrtf(var + 1e-5f);
    int db = lane*4;
    float4 r;
    r.x=(x.x-mean)*rs*g[db+0]+b[db+0];
    r.y=(x.y-mean)*rs*g[db+1]+b[db+1];
    r.z=(x.z-mean)*rs*g[db+2]+b[db+2];
    r.w=(x.w-mean)*rs*g[db+3]+b[db+3];
    *(float4*)(out + (size_t)row*D_ + db) = r;
}

__global__ __launch_bounds__(256) void ln3_k(const float* __restrict__ in,
    const float* __restrict__ g3, const float* __restrict__ b3, float* __restrict__ states,
    const float* __restrict__ g4, const float* __restrict__ b4, float* __restrict__ fsout)
{
    int row  = blockIdx.x*4 + (threadIdx.x>>6);
    int lane = threadIdx.x & 63;
    const float* ip = in + (size_t)row*D_ + lane*4;
    float4 x = *(const float4*)ip;
    float s  = x.x+x.y+x.z+x.w;
    float s2 = x.x*x.x + x.y*x.y + x.z*x.z + x.w*x.w;
    #pragma unroll
    for (int o=1;o<64;o<<=1){ s += __shfl_xor(s,o); s2 += __shfl_xor(s2,o); }
    float mean = s * (1.f/256.f);
    float var  = s2 * (1.f/256.f) - mean*mean;
    float rs = rsqrtf(var + 1e-5f);
    int db = lane*4;
    float4 st;
    st.x=(x.x-mean)*rs*g3[db+0]+b3[db+0];
    st.y=(x.y-mean)*rs*g3[db+1]+b3[db+1];
    st.z=(x.z-mean)*rs*g3[db+2]+b3[db+2];
    st.w=(x.w-mean)*rs*g3[db+3]+b3[db+3];
    *(float4*)(states + (size_t)row*D_ + db) = st;

    if ((row & (T_-1)) == T_-1){
        float u  = st.x+st.y+st.z+st.w;
        float u2 = st.x*st.x + st.y*st.y + st.z*st.z + st.w*st.w;
        #pragma unroll
        for (int o=1;o<64;o<<=1){ u += __shfl_xor(u,o); u2 += __shfl_xor(u2,o); }
        float m2 = u * (1.f/256.f);
        float v2 = u2 * (1.f/256.f) - m2*m2;
        float r2 = rsqrtf(v2 + 1e-5f);
        float4 fs;
        fs.x=(st.x-m2)*r2*g4[db+0]+b4[db+0];
        fs.y=(st.y-m2)*r2*g4[db+1]+b4[db+1];
        fs.z=(st.z-m2)*r2*g4[db+2]+b4[db+2];
        fs.w=(st.w-m2)*r2*g4[db+3]+b4[db+3];
        *(float4*)(fsout + (size_t)(row>>11)*D_ + db) = fs;
    }
}

// ---------------------------------------------------------------------------
extern "C" void kernel_launch(void* const* d_in, const int* in_sizes, int n_in,
                              void* d_out, int out_size, void* d_ws, size_t ws_size,
                              hipStream_t stream)
{
    const float* X     = (const float*)d_in[0];
    const float* SEQ   = (const float*)d_in[1];
    const float* conv_w= (const float*)d_in[3];
    const float* conv_b= (const float*)d_in[4];
    const float* qkv_w = (const float*)d_in[5];
    const float* qkv_b = (const float*)d_in[6];
    const float* mo_w  = (const float*)d_in[7];
    const float* mo_b  = (const float*)d_in[8];
    const float* fg_w  = (const float*)d_in[9];
    const float* fg_b  = (const float*)d_in[10];
    const float* gkv_w = (const float*)d_in[11];
    const float* gkv_b = (const float*)d_in[12];
    const float* go_w  = (const float*)d_in[13];
    const float* go_b  = (const float*)d_in[14];
    const float* comb_w= (const float*)d_in[15];
    const float* comb_b= (const float*)d_in[16];
    const float* ffn1_w= (const float*)d_in[17];
    const float* ffn1_b= (const float*)d_in[18];
    const float* ffn2_w= (const float*)d_in[19];
    const float* ffn2_b= (const float*)d_in[20];
    const float* tr1_w = (const float*)d_in[21];
    const float* tr1_b = (const float*)d_in[22];
    const float* tr2_w = (const float*)d_in[23];
    const float* tr2_b = (const float*)d_in[24];
    const float* p2s_w = (const float*)d_in[25];
    const float* p2s_b = (const float*)d_in[26];
    const float* s2p_w = (const float*)d_in[27];
    const float* s2p_b = (const float*)d_in[28];
    const float* ln1_g = (const float*)d_in[29];
    const float* ln1_b = (const float*)d_in[30];
    const float* ln2_g = (const float*)d_in[31];
    const float* ln2_b = (const float*)d_in[32];
    const float* ln3_g = (const float*)d_in[33];
    const float* ln3_b = (const float*)d_in[34];
    const float* ln4_g = (const float*)d_in[35];
    const float* ln4_b = (const float*)d_in[36];

    float* ws   = (float*)d_ws;
    float* QKVG = ws;                          // M*1280  (reused later as H2: M*1024)
    float* H1   = QKVG + (size_t)M_*1280;      // M*512   (aliased as scan-carry space)
    float* BUF2 = H1   + (size_t)M_*512;
    float* BUF3 = BUF2 + (size_t)M_*256;
    float* BUF4 = BUF3 + (size_t)M_*256;
    float* BUF5 = BUF4 + (size_t)M_*256;       // VT (steps 1-4) -> CONC -> PR
    float* BUF6 = BUF5 + (size_t)M_*256;
    float* H2   = QKVG;
    float* VT   = BUF5;                        // V^T [b][h][d][t], live steps 1-4

    float* CAR0 = H1;
    float* CAR1 = H1 + (size_t)B_*NC_*D_;

    float* out_pr = (float*)d_out;
    float* out_fs = out_pr + (size_t)M_*256;
    float* out_tj = out_fs + B_*256;

    const dim3 blk256(256);
    const dim3 scan_grid(NC_, B_);
    const int NR = M_/64;   // 128 row tiles

    // 1. qkv projection -> QKVG[:, 0:768) (+ V^T side write)
    gemm_k<<<dim3(NR*12), blk256, 0, stream>>>(
        X, qkv_w, 256, 256,  nullptr,nullptr,0,0,  nullptr,nullptr,0,0,
        qkv_b, nullptr, QKVG, 1280, OP_NONE, 12, VT);
    // 2. gkv projection -> QKVG[:, 768:1280)
    gemm_k<<<dim3(NR*8), blk256, 0, stream>>>(
        X, gkv_w, 256, 256,  nullptr,nullptr,0,0,  nullptr,nullptr,0,0,
        gkv_b, nullptr, QKVG+768, 1280, OP_NONE, 8, nullptr);
    // 3. local_history (depthwise conv) -> BUF2
    conv_k<<<dim3(M_*D_/256), blk256, 0, stream>>>(X, conv_w, conv_b, BUF2);
    // 4. banded attention (MFMA) -> BUF3
    attn_k<<<dim3(T_/64, H_, B_), blk256, 0, stream>>>(QKVG, VT, BUF3);
    // 5. mo projection -> BUF4
    gemm_k<<<dim3(NR*4), blk256, 0, stream>>>(
        BUF3, mo_w, 256, 256,  nullptr,nullptr,0,0,  nullptr,nullptr,0,0,
        mo_b, nullptr, BUF4, 256, OP_NONE, 4, nullptr);
    // 6. concepts scan (chunked) -> BUF5
    scan1_p1<<<scan_grid, blk256, 0, stream>>>(QKVG, CAR0, CAR1);
    scan1_p2<<<dim3(4), blk256, 0, stream>>>(CAR0, CAR1);
    scan1_p3<<<scan_grid, blk256, 0, stream>>>(QKVG, CAR0, CAR1, BUF5);
    // 7. global_out -> BUF6
    gemm_k<<<dim3(NR*4), blk256, 0, stream>>>(
        BUF5, go_w, 256, 256,  nullptr,nullptr,0,0,  nullptr,nullptr,0,0,
        go_b, nullptr, BUF6, 256, OP_NONE, 4, nullptr);
    // 8. medium_out = MED2 * sigmoid([X,MED2]@fg^T + b) -> BUF3
    gemm_k<<<dim3(NR*4), blk256, 0, stream>>>(
        X, fg_w, 512, 256,  BUF4, fg_w+256, 512, 256,  nullptr,nullptr,0,0,
        fg_b, BUF4, BUF3, 256, OP_SIGMUL, 4, nullptr);
    // 9. pre_ln1 = X + [LH,MOUT,GOUT]@comb^T + b -> BUF4
    gemm_k<<<dim3(NR*4), blk256, 0, stream>>>(
        BUF2, comb_w, 768, 256,  BUF3, comb_w+256, 768, 256,  BUF6, comb_w+512, 768, 256,
        comb_b, X, BUF4, 256, OP_ADDAUX, 4, nullptr);
    // 10. pr = LN1 -> BUF5
    ln_k<<<dim3(M_/4), blk256, 0, stream>>>(BUF4, ln1_g, ln1_b, BUF5);
    // 11. global_summary EMA -> BUF6, final_traj -> out
    ema_p1<<<scan_grid, blk256, 0, stream>>>(BUF5, CAR0, 0.1f);
    ema_p2<<<dim3(4), blk256, 0, stream>>>(CAR0, out_tj);
    ema_p3<<<scan_grid, blk256, 0, stream>>>(BUF5, CAR0, BUF6, 0.1f);
    // 12. cs1 = pr + 0.3*(pr@p2s^T + b) -> BUF2
    gemm_k<<<dim3(NR*4), blk256, 0, stream>>>(
        BUF5, p2s_w, 256, 256,  nullptr,nullptr,0,0,  nullptr,nullptr,0,0,
        p2s_b, BUF5, BUF2, 256, OP_AXPBY, 4, nullptr);
    // 13. H1 = gelu(cs1@tr1a + gsum@tr1b + b)
    gemm_k<<<dim3(NR*8), blk256, 0, stream>>>(
        BUF2, tr1_w, 512, 256,  BUF6, tr1_w+256, 512, 256,  nullptr,nullptr,0,0,
        tr1_b, nullptr, H1, 512, OP_GELU, 8, nullptr);
    // 14. scaled = 0.5*tanh(H1@tr2^T + b) -> BUF3
    gemm_k<<<dim3(NR*4), blk256, 0, stream>>>(
        H1, tr2_w, 512, 512,  nullptr,nullptr,0,0,  nullptr,nullptr,0,0,
        tr2_b, nullptr, BUF3, 256, OP_TANHHALF, 4, nullptr);
    // 15. state EMA + decayed initial -> BUF4 (pre_ln3)
    ema_p1<<<scan_grid, blk256, 0, stream>>>(BUF3, CAR0, 1.0f);
    ema_p2<<<dim3(4), blk256, 0, stream>>>(CAR0, nullptr);
    ema_p3_state<<<scan_grid, blk256, 0, stream>>>(BUF3, CAR0, SEQ, BUF4);
    // 16. states = LN3 -> BUF6; final_state = LN4(states[-1]) -> out
    ln3_k<<<dim3(M_/4), blk256, 0, stream>>>(BUF4, ln3_g, ln3_b, BUF6, ln4_g, ln4_b, out_fs);
    // 17. ffn_in = pr + 0.3*(states@s2p^T + b) -> BUF2
    gemm_k<<<dim3(NR*4), blk256, 0, stream>>>(
        BUF6, s2p_w, 256, 256,  nullptr,nullptr,0,0,  nullptr,nullptr,0,0,
        s2p_b, BUF5, BUF2, 256, OP_AXPBY, 4, nullptr);
    // 18. H2 = gelu(ffn_in@ffn1^T + b)
    gemm_k<<<dim3(NR*16), blk256, 0, stream>>>(
        BUF2, ffn1_w, 256, 256,  nullptr,nullptr,0,0,  nullptr,nullptr,0,0,
        ffn1_b, nullptr, H2, 1024, OP_GELU, 16, nullptr);
    // 19. pre_ln2 = pr + H2@ffn2^T + b -> BUF3
    gemm_k<<<dim3(NR*4), blk256, 0, stream>>>(
        H2, ffn2_w, 1024, 1024,  nullptr,nullptr,0,0,  nullptr,nullptr,0,0,
        ffn2_b, BUF5, BUF3, 256, OP_ADDAUX, 4, nullptr);
    // 20. pr_out = LN2 -> d_out
    ln_k<<<dim3(M_/4), blk256, 0, stream>>>(BUF3, ln2_g, ln2_b, out_pr);
}

// Round 5
// 275.225 us; speedup vs baseline: 4.0405x; 1.1759x over previous
//
#include <hip/hip_runtime.h>
#include <hip/hip_bf16.h>
#include <math.h>

#define D_  256
#define T_  2048
#define B_  4
#define M_  (B_*T_)
#define H_  4
#define HD_ 64

#define NC_ 64          // scan chunks
#define LCH (T_/NC_)    // 32 steps per chunk

enum { OP_NONE=0, OP_SIGMUL=1, OP_ADDAUX=2, OP_AXPBY=3, OP_GELU=4, OP_TANHHALF=5 };

typedef short short8 __attribute__((ext_vector_type(8)));
typedef float f32x4  __attribute__((ext_vector_type(4)));

__device__ __forceinline__ float gelu_f(float x){ return 0.5f*x*(1.0f+erff(x*0.70710678118654752f)); }
__device__ __forceinline__ float sigmoid_f(float x){ return 1.0f/(1.0f+expf(-x)); }

// pack 2 fp32 -> 2 bf16 (RNE) in one uint (low ushort = a, high = b)
__device__ __forceinline__ unsigned pk2(float a, float b){
    __hip_bfloat162 h = __float22bfloat162_rn(make_float2(a,b));
    union { __hip_bfloat162 h; unsigned u; } c; c.h = h; return c.u;
}

// ---------------------------------------------------------------------------
// bf16 MFMA GEMM, register-staged pipeline:
//   barrier -> regs->LDS (bf16) -> barrier -> issue next tile's 8 loads -> MFMA
// Loads for tile t+1 stay in flight across MFMA(t) and drain at the next
// __syncthreads (its vmcnt(0)), hiding global latency. Tile 64x64, BK=64,
// 4 waves (2x2), mfma_f32_16x16x32_bf16, XCD-chunked block swizzle.
// ---------------------------------------------------------------------------
__global__ __launch_bounds__(256) void gemm_k(
    const float* __restrict__ A0, const float* __restrict__ W0, int ldw0, int K0,
    const float* __restrict__ A1, const float* __restrict__ W1, int ldw1, int K1,
    const float* __restrict__ A2, const float* __restrict__ W2, int ldw2, int K2,
    const float* __restrict__ bias, const float* __restrict__ aux,
    float* __restrict__ C, int ldc, int op, int ncol, float* __restrict__ vt)
{
    __shared__ unsigned short As[64*64];
    __shared__ unsigned short Ws[64*64];

    const int q8   = gridDim.x >> 3;
    const int lid  = (blockIdx.x & 7)*q8 + (blockIdx.x >> 3);
    const int brow = lid / ncol;
    const int bcol = lid - brow*ncol;
    const int row0 = brow*64, col0 = bcol*64;

    const int tid  = threadIdx.x;
    const int lane = tid & 63, wid = tid >> 6;
    const int wm = (wid >> 1)*32, wn = (wid & 1)*32;
    const int l15 = lane & 15, l4 = lane >> 4;
    const int srow = tid >> 3;          // 0..31
    const int sc8  = (tid & 7) * 8;

    f32x4 acc[2][2];
    #pragma unroll
    for (int i=0;i<2;++i)
        #pragma unroll
        for (int j=0;j<2;++j) acc[i][j] = (f32x4){0.f,0.f,0.f,0.f};

    float4 ra0,ra1,ra2,ra3, rw0,rw1,rw2,rw3;

    auto loadtile = [&](const float* A, const float* W, int ldw, int K, int kb){
        const float* ga = A + (size_t)(row0+srow)*K + kb + sc8;
        const float* ga2 = ga + (size_t)32*K;
        const float* gw = W + (size_t)(col0+srow)*ldw + kb + sc8;
        const float* gw2 = gw + (size_t)32*ldw;
        ra0 = *(const float4*)ga;  ra1 = *(const float4*)(ga+4);
        ra2 = *(const float4*)ga2; ra3 = *(const float4*)(ga2+4);
        rw0 = *(const float4*)gw;  rw1 = *(const float4*)(gw+4);
        rw2 = *(const float4*)gw2; rw3 = *(const float4*)(gw2+4);
    };
    auto storetile = [&](){
        const int i0 = (srow*64 + sc8) ^ ((srow&7)<<3);
        *(uint4*)&As[i0] = (uint4){pk2(ra0.x,ra0.y),pk2(ra0.z,ra0.w),pk2(ra1.x,ra1.y),pk2(ra1.z,ra1.w)};
        *(uint4*)&Ws[i0] = (uint4){pk2(rw0.x,rw0.y),pk2(rw0.z,rw0.w),pk2(rw1.x,rw1.y),pk2(rw1.z,rw1.w)};
        const int r2 = srow + 32;
        const int i1 = (r2*64 + sc8) ^ ((r2&7)<<3);
        *(uint4*)&As[i1] = (uint4){pk2(ra2.x,ra2.y),pk2(ra2.z,ra2.w),pk2(ra3.x,ra3.y),pk2(ra3.z,ra3.w)};
        *(uint4*)&Ws[i1] = (uint4){pk2(rw2.x,rw2.y),pk2(rw2.z,rw2.w),pk2(rw3.x,rw3.y),pk2(rw3.z,rw3.w)};
    };
    auto mfma_tile = [&](){
        #pragma unroll
        for (int ks=0;ks<2;++ks){
            const int koff = ks*32 + l4*8;
            short8 af[2], bf[2];
            #pragma unroll
            for (int f=0;f<2;++f){
                const int ar = wm + f*16 + l15;
                af[f] = *(const short8*)&As[(ar*64 + koff) ^ ((ar&7)<<3)];
                const int brn = wn + f*16 + l15;
                bf[f] = *(const short8*)&Ws[(brn*64 + koff) ^ ((brn&7)<<3)];
            }
            #pragma unroll
            for (int fm=0;fm<2;++fm)
                #pragma unroll
                for (int fn=0;fn<2;++fn)
                    acc[fm][fn] = __builtin_amdgcn_mfma_f32_16x16x32_bf16(
                        af[fm], bf[fn], acc[fm][fn], 0, 0, 0);
        }
    };

    // flattened software pipeline across the (up to 3) fused operands
    const float* Ac = A0; const float* Wc = W0; int ldwc = ldw0, Kc = K0, kb = 0;
    loadtile(Ac, Wc, ldwc, Kc, 0);
    while (true){
        __syncthreads();            // drains in-flight loads (vmcnt 0) + LDS free
        storetile();
        __syncthreads();            // staged tile visible
        int nkb = kb + 64;
        const float* nA = Ac; const float* nW = Wc; int nld = ldwc, nK = Kc;
        bool have_next = true;
        if (nkb >= Kc){
            if (Ac == A0 && A1){ nA = A1; nW = W1; nld = ldw1; nK = K1; nkb = 0; }
            else if (Ac == A1 && A2){ nA = A2; nW = W2; nld = ldw2; nK = K2; nkb = 0; }
            else have_next = false;
        }
        if (have_next) loadtile(nA, nW, nld, nK, nkb);   // in flight across MFMA
        mfma_tile();
        if (!have_next) break;
        Ac = nA; Wc = nW; ldwc = nld; Kc = nK; kb = nkb;
    }

    // epilogue: D mapping col = lane&15, row = (lane>>4)*4 + j
    #pragma unroll
    for (int fn=0;fn<2;++fn){
        const int n = col0 + wn + fn*16 + l15;
        const float bv = bias[n];
        const bool vwr = (vt != nullptr) && (n >= 512) && (n < 768);
        #pragma unroll
        for (int fm=0;fm<2;++fm){
            #pragma unroll
            for (int j=0;j<4;++j){
                const int m = row0 + wm + fm*16 + l4*4 + j;
                float v = acc[fm][fn][j] + bv;
                if (op==OP_GELU)          v = gelu_f(v);
                else if (op==OP_TANHHALF) v = 0.5f*tanhf(v);
                else if (op==OP_SIGMUL)   v = aux[(size_t)m*D_ + n]*sigmoid_f(v);
                else if (op==OP_ADDAUX)   v = v + aux[(size_t)m*D_ + n];
                else if (op==OP_AXPBY)    v = aux[(size_t)m*D_ + n] + 0.3f*v;
                C[(size_t)m*ldc + n] = v;
                if (vwr){
                    const int hh = (n-512)>>6, dd = (n-512)&63;
                    const int bb = m >> 11, tt = m & (T_-1);
                    vt[(((size_t)(bb*H_ + hh))*64 + dd)*T_ + tt] = v;
                }
            }
        }
    }
}

// ---------------------------------------------------------------------------
// Depthwise causal conv, K=8, pad left 7.
// ---------------------------------------------------------------------------
__global__ __launch_bounds__(256) void conv_k(const float* __restrict__ X,
    const float* __restrict__ w, const float* __restrict__ bias, float* __restrict__ out)
{
    int idx = blockIdx.x*256 + threadIdx.x;
    int d = idx & (D_-1);
    int bt = idx >> 8;
    int t = bt & (T_-1);
    float acc = bias[d];
    const float* xp = X + (size_t)bt*D_ + d;
    const float* wp = w + d*8;
    #pragma unroll
    for (int j=0;j<8;++j){
        int tt = t - 7 + j;
        if (tt >= 0) acc += xp[(size_t)(j-7)*D_] * wp[j];
    }
    out[idx] = acc;
}

// ---------------------------------------------------------------------------
// MFMA banded attention. Per block: (b, h, 64-query tile), 4 waves.
// ---------------------------------------------------------------------------
__global__ __launch_bounds__(256) void attn_k(const float* __restrict__ QKVG,
    const float* __restrict__ VT, float* __restrict__ MED)
{
    __shared__ unsigned short Kl[128*64];
    __shared__ unsigned short Ql[64*64];
    __shared__ unsigned short Vl[64*128];
    const int b = blockIdx.z, h = blockIdx.y;
    const int t0 = blockIdx.x * 64;
    const int kb0 = t0 - 64;
    const int tid = threadIdx.x;

    {   // stage K (128 key rows x 64 dims) and Q (64 rows)
        const int r0 = tid >> 3, c8 = (tid & 7) * 8;
        #pragma unroll
        for (int rep=0;rep<4;++rep){
            const int r = r0 + rep*32;
            const int kg = kb0 + r;
            uint4 pk = {0,0,0,0};
            if (kg >= 0){
                const float* gp = QKVG + ((size_t)(b*T_ + kg))*1280 + 256 + h*HD_ + c8;
                float4 x0 = *(const float4*)gp, x1 = *(const float4*)(gp+4);
                pk = (uint4){pk2(x0.x,x0.y),pk2(x0.z,x0.w),pk2(x1.x,x1.y),pk2(x1.z,x1.w)};
            }
            *(uint4*)&Kl[(r*64 + c8) ^ ((r&7)<<3)] = pk;
        }
        #pragma unroll
        for (int rep=0;rep<2;++rep){
            const int r = r0 + rep*32;
            const float* gp = QKVG + ((size_t)(b*T_ + t0 + r))*1280 + h*HD_ + c8;
            float4 x0 = *(const float4*)gp, x1 = *(const float4*)(gp+4);
            uint4 pq = (uint4){pk2(x0.x,x0.y),pk2(x0.z,x0.w),pk2(x1.x,x1.y),pk2(x1.z,x1.w)};
            *(uint4*)&Ql[(r*64 + c8) ^ ((r&7)<<3)] = pq;
        }
    }
    {   // stage VT (64 dims x 128 keys)
        const int d0 = tid >> 4, c8 = (tid & 15) * 8;
        #pragma unroll
        for (int rep=0;rep<4;++rep){
            const int d = d0 + rep*16;
            uint4 pv = {0,0,0,0};
            if (kb0 + c8 >= 0){
                const float* gp = VT + ((size_t)(b*H_ + h)*64 + d)*T_ + kb0 + c8;
                float4 x0 = *(const float4*)gp, x1 = *(const float4*)(gp+4);
                pv = (uint4){pk2(x0.x,x0.y),pk2(x0.z,x0.w),pk2(x1.x,x1.y),pk2(x1.z,x1.w)};
            }
            *(uint4*)&Vl[(d*128 + c8) ^ ((d&7)<<3)] = pv;
        }
    }
    __syncthreads();

    const int lane = tid & 63, w = tid >> 6;
    const int l15 = lane & 15, l4 = lane >> 4;

    short8 bq[2];
    {
        const int qr = w*16 + l15;
        bq[0] = *(const short8*)&Ql[(qr*64 +      l4*8) ^ ((qr&7)<<3)];
        bq[1] = *(const short8*)&Ql[(qr*64 + 32 + l4*8) ^ ((qr&7)<<3)];
    }

    f32x4 s[8];
    #pragma unroll
    for (int kf=0;kf<8;++kf){
        const int kr = kf*16 + l15;
        short8 a0 = *(const short8*)&Kl[(kr*64 +      l4*8) ^ ((kr&7)<<3)];
        short8 a1 = *(const short8*)&Kl[(kr*64 + 32 + l4*8) ^ ((kr&7)<<3)];
        f32x4 acc = (f32x4){0.f,0.f,0.f,0.f};
        acc = __builtin_amdgcn_mfma_f32_16x16x32_bf16(a0, bq[0], acc, 0,0,0);
        acc = __builtin_amdgcn_mfma_f32_16x16x32_bf16(a1, bq[1], acc, 0,0,0);
        s[kf] = acc;
    }

    const int qg = t0 + w*16 + l15;
    float m = -1e30f;
    #pragma unroll
    for (int kf=0;kf<8;++kf){
        #pragma unroll
        for (int j=0;j<4;++j){
            const int kg = kb0 + kf*16 + l4*4 + j;
            const int diff = qg - kg;
            const float v = (kg >= 0 && diff >= 0 && diff < 64) ? s[kf][j]*0.125f : -1e30f;
            s[kf][j] = v;
            m = fmaxf(m, v);
        }
    }
    m = fmaxf(m, __shfl_xor(m,16));
    m = fmaxf(m, __shfl_xor(m,32));
    float lsum = 0.f;
    unsigned lo[8], hi[8];
    #pragma unroll
    for (int kf=0;kf<8;++kf){
        const float p0 = expf(s[kf][0]-m), p1 = expf(s[kf][1]-m);
        const float p2 = expf(s[kf][2]-m), p3 = expf(s[kf][3]-m);
        lsum += (p0+p1)+(p2+p3);
        lo[kf] = pk2(p0,p1);
        hi[kf] = pk2(p2,p3);
    }
    lsum += __shfl_xor(lsum,16);
    lsum += __shfl_xor(lsum,32);
    const float inv = 1.f/lsum;

    f32x4 o[4];
    #pragma unroll
    for (int df=0;df<4;++df) o[df] = (f32x4){0.f,0.f,0.f,0.f};
    const int baseLane = l15 + ((l4&1)<<5);
    const bool hiHalf = (l4>>1) != 0;
    #pragma unroll
    for (int kb=0;kb<4;++kb){
        const int x0 = __shfl((int)lo[2*kb],   baseLane);
        const int x1 = __shfl((int)hi[2*kb],   baseLane);
        const int x2 = __shfl((int)lo[2*kb],   baseLane+16);
        const int x3 = __shfl((int)hi[2*kb],   baseLane+16);
        const int y0 = __shfl((int)lo[2*kb+1], baseLane);
        const int y1 = __shfl((int)hi[2*kb+1], baseLane);
        const int y2 = __shfl((int)lo[2*kb+1], baseLane+16);
        const int y3 = __shfl((int)hi[2*kb+1], baseLane+16);
        int4 afi;
        afi.x = hiHalf ? y0 : x0;
        afi.y = hiHalf ? y1 : x1;
        afi.z = hiHalf ? y2 : x2;
        afi.w = hiHalf ? y3 : x3;
        union { int4 i; short8 s; } cv; cv.i = afi;
        #pragma unroll
        for (int df=0;df<4;++df){
            const int vr = df*16 + l15;
            short8 bv = *(const short8*)&Vl[(vr*128 + kb*32 + l4*8) ^ ((vr&7)<<3)];
            o[df] = __builtin_amdgcn_mfma_f32_16x16x32_bf16(cv.s, bv, o[df], 0,0,0);
        }
    }

    #pragma unroll
    for (int j=0;j<4;++j){
        const float invj = __shfl(inv, l4*4 + j);
        const int mrow = b*T_ + t0 + w*16 + l4*4 + j;
        float* op = MED + (size_t)mrow*D_ + h*HD_ + l15;
        #pragma unroll
        for (int df=0;df<4;++df)
            op[df*16] = o[df][j] * invj;
    }
}

// ---------------------------------------------------------------------------
// Chunked parallel scans.
// ---------------------------------------------------------------------------
__global__ __launch_bounds__(256) void scan1_p1(const float* __restrict__ QKVG,
    float* __restrict__ CA, float* __restrict__ CC)
{
    const int d = threadIdx.x, c = blockIdx.x, b = blockIdx.y;
    const float* base = QKVG + ((size_t)(b*T_ + c*LCH))*1280;
    float sgk=0.f, sgkv=0.f;
    for (int t=0;t<LCH;++t){
        float gk = base[(size_t)t*1280 + 768 + d];
        gk = gk > 0.f ? gk + 1.f : expf(gk);
        float gv = base[(size_t)t*1280 + 1024 + d];
        sgk += gk; sgkv += gk*gv;
    }
    CA[((size_t)b*NC_ + c)*D_ + d] = sgk;
    CC[((size_t)b*NC_ + c)*D_ + d] = sgkv;
}

__global__ void scan1_p2(float* __restrict__ CA, float* __restrict__ CC)
{
    int idx = blockIdx.x*256 + threadIdx.x;
    int d = idx & (D_-1), b = idx >> 8;
    float sa=0.f, sc=0.f;
    for (int c=0;c<NC_;++c){
        size_t o = ((size_t)b*NC_ + c)*D_ + d;
        float a = CA[o], cc = CC[o];
        CA[o] = sa; CC[o] = sc;
        sa += a; sc += cc;
    }
}

__global__ __launch_bounds__(256) void scan1_p3(const float* __restrict__ QKVG,
    const float* __restrict__ CA, const float* __restrict__ CC, float* __restrict__ CONC)
{
    const int d = threadIdx.x, c = blockIdx.x, b = blockIdx.y;
    float sgk  = CA[((size_t)b*NC_ + c)*D_ + d];
    float sgkv = CC[((size_t)b*NC_ + c)*D_ + d];
    const float* base = QKVG + ((size_t)(b*T_ + c*LCH))*1280;
    float* out = CONC + ((size_t)(b*T_ + c*LCH))*D_ + d;
    for (int t=0;t<LCH;++t){
        float gk = base[(size_t)t*1280 + 768 + d];
        gk = gk > 0.f ? gk + 1.f : expf(gk);
        float gv = base[(size_t)t*1280 + 1024 + d];
        sgk += gk; sgkv += gk*gv;
        out[(size_t)t*D_] = sgkv / (sgk + 1e-5f);
    }
}

__global__ __launch_bounds__(256) void ema_p1(const float* __restrict__ X,
    float* __restrict__ CARRY, float alpha)
{
    const int d = threadIdx.x, c = blockIdx.x, b = blockIdx.y;
    const float* xp = X + ((size_t)(b*T_ + c*LCH))*D_ + d;
    float g = 0.f;
    for (int t=0;t<LCH;++t) g = 0.9f*g + alpha*xp[(size_t)t*D_];
    CARRY[((size_t)b*NC_ + c)*D_ + d] = g;
}

__global__ void ema_p2(float* __restrict__ CARRY, float* __restrict__ traj)
{
    int idx = blockIdx.x*256 + threadIdx.x;
    int d = idx & (D_-1), b = idx >> 8;
    const float dL = powf(0.9f, (float)LCH);
    float run = 0.f;
    for (int c=0;c<NC_;++c){
        size_t o = ((size_t)b*NC_ + c)*D_ + d;
        float loc = CARRY[o];
        CARRY[o] = run;
        run = loc + dL*run;
    }
    if (traj) traj[b*D_ + d] = run;
}

__global__ __launch_bounds__(256) void ema_p3(const float* __restrict__ X,
    const float* __restrict__ CARRY, float* __restrict__ OUT, float alpha)
{
    const int d = threadIdx.x, c = blockIdx.x, b = blockIdx.y;
    float g = CARRY[((size_t)b*NC_ + c)*D_ + d];
    const float* xp = X + ((size_t)(b*T_ + c*LCH))*D_ + d;
    float* op = OUT + ((size_t)(b*T_ + c*LCH))*D_ + d;
    for (int t=0;t<LCH;++t){
        g = 0.9f*g + alpha*xp[(size_t)t*D_];
        op[(size_t)t*D_] = g;
    }
}

__global__ __launch_bounds__(256) void ema_p3_state(const float* __restrict__ X,
    const float* __restrict__ CARRY, const float* __restrict__ SEQ, float* __restrict__ OUT)
{
    const int d = threadIdx.x, c = blockIdx.x, b = blockIdx.y;
    float a = CARRY[((size_t)b*NC_ + c)*D_ + d];
    const float ss = SEQ[b*D_ + d];
    float dp = powf(0.9f, (float)(c*LCH + 1));
    const float* xp = X + ((size_t)(b*T_ + c*LCH))*D_ + d;
    float* op = OUT + ((size_t)(b*T_ + c*LCH))*D_ + d;
    for (int t=0;t<LCH;++t){
        a = 0.9f*a + xp[(size_t)t*D_];
        op[(size_t)t*D_] = fmaf(ss, dp, a);
        dp *= 0.9f;
    }
}

// ---------------------------------------------------------------------------
// LayerNorms
// ---------------------------------------------------------------------------
__global__ __launch_bounds__(256) void ln_k(const float* __restrict__ in,
    const float* __restrict__ g, const float* __restrict__ b, float* __restrict__ out)
{
    int row  = blockIdx.x*4 + (threadIdx.x>>6);
    int lane = threadIdx.x & 63;
    const float* ip = in + (size_t)row*D_ + lane*4;
    float4 x = *(const float4*)ip;
    float s  = x.x+x.y+x.z+x.w;
    float s2 = x.x*x.x + x.y*x.y + x.z*x.z + x.w*x.w;
    #pragma unroll
    for (int o=1;o<64;o<<=1){ s += __shfl_xor(s,o); s2 += __shfl_xor(s2,o); }
    float mean = s * (1.f/256.f);
    float var  = s2 * (1.f/256.f) - mean*mean;
    float rs = rsqrtf(var + 1e-5f);
    int db = lane*4;
    float4 r;
    r.x=(x.x-mean)*rs*g[db+0]+b[db+0];
    r.y=(x.y-mean)*rs*g[db+1]+b[db+1];
    r.z=(x.z-mean)*rs*g[db+2]+b[db+2];
    r.w=(x.w-mean)*rs*g[db+3]+b[db+3];
    *(float4*)(out + (size_t)row*D_ + db) = r;
}

__global__ __launch_bounds__(256) void ln3_k(const float* __restrict__ in,
    const float* __restrict__ g3, const float* __restrict__ b3, float* __restrict__ states,
    const float* __restrict__ g4, const float* __restrict__ b4, float* __restrict__ fsout)
{
    int row  = blockIdx.x*4 + (threadIdx.x>>6);
    int lane = threadIdx.x & 63;
    const float* ip = in + (size_t)row*D_ + lane*4;
    float4 x = *(const float4*)ip;
    float s  = x.x+x.y+x.z+x.w;
    float s2 = x.x*x.x + x.y*x.y + x.z*x.z + x.w*x.w;
    #pragma unroll
    for (int o=1;o<64;o<<=1){ s += __shfl_xor(s,o); s2 += __shfl_xor(s2,o); }
    float mean = s * (1.f/256.f);
    float var  = s2 * (1.f/256.f) - mean*mean;
    float rs = rsqrtf(var + 1e-5f);
    int db = lane*4;
    float4 st;
    st.x=(x.x-mean)*rs*g3[db+0]+b3[db+0];
    st.y=(x.y-mean)*rs*g3[db+1]+b3[db+1];
    st.z=(x.z-mean)*rs*g3[db+2]+b3[db+2];
    st.w=(x.w-mean)*rs*g3[db+3]+b3[db+3];
    *(float4*)(states + (size_t)row*D_ + db) = st;

    if ((row & (T_-1)) == T_-1){
        float u  = st.x+st.y+st.z+st.w;
        float u2 = st.x*st.x + st.y*st.y + st.z*st.z + st.w*st.w;
        #pragma unroll
        for (int o=1;o<64;o<<=1){ u += __shfl_xor(u,o); u2 += __shfl_xor(u2,o); }
        float m2 = u * (1.f/256.f);
        float v2 = u2 * (1.f/256.f) - m2*m2;
        float r2 = rsqrtf(v2 + 1e-5f);
        float4 fs;
        fs.x=(st.x-m2)*r2*g4[db+0]+b4[db+0];
        fs.y=(st.y-m2)*r2*g4[db+1]+b4[db+1];
        fs.z=(st.z-m2)*r2*g4[db+2]+b4[db+2];
        fs.w=(st.w-m2)*r2*g4[db+3]+b4[db+3];
        *(float4*)(fsout + (size_t)(row>>11)*D_ + db) = fs;
    }
}

// ---------------------------------------------------------------------------
extern "C" void kernel_launch(void* const* d_in, const int* in_sizes, int n_in,
                              void* d_out, int out_size, void* d_ws, size_t ws_size,
                              hipStream_t stream)
{
    const float* X     = (const float*)d_in[0];
    const float* SEQ   = (const float*)d_in[1];
    const float* conv_w= (const float*)d_in[3];
    const float* conv_b= (const float*)d_in[4];
    const float* qkv_w = (const float*)d_in[5];
    const float* qkv_b = (const float*)d_in[6];
    const float* mo_w  = (const float*)d_in[7];
    const float* mo_b  = (const float*)d_in[8];
    const float* fg_w  = (const float*)d_in[9];
    const float* fg_b  = (const float*)d_in[10];
    const float* gkv_w = (const float*)d_in[11];
    const float* gkv_b = (const float*)d_in[12];
    const float* go_w  = (const float*)d_in[13];
    const float* go_b  = (const float*)d_in[14];
    const float* comb_w= (const float*)d_in[15];
    const float* comb_b= (const float*)d_in[16];
    const float* ffn1_w= (const float*)d_in[17];
    const float* ffn1_b= (const float*)d_in[18];
    const float* ffn2_w= (const float*)d_in[19];
    const float* ffn2_b= (const float*)d_in[20];
    const float* tr1_w = (const float*)d_in[21];
    const float* tr1_b = (const float*)d_in[22];
    const float* tr2_w = (const float*)d_in[23];
    const float* tr2_b = (const float*)d_in[24];
    const float* p2s_w = (const float*)d_in[25];
    const float* p2s_b = (const float*)d_in[26];
    const float* s2p_w = (const float*)d_in[27];
    const float* s2p_b = (const float*)d_in[28];
    const float* ln1_g = (const float*)d_in[29];
    const float* ln1_b = (const float*)d_in[30];
    const float* ln2_g = (const float*)d_in[31];
    const float* ln2_b = (const float*)d_in[32];
    const float* ln3_g = (const float*)d_in[33];
    const float* ln3_b = (const float*)d_in[34];
    const float* ln4_g = (const float*)d_in[35];
    const float* ln4_b = (const float*)d_in[36];

    float* ws   = (float*)d_ws;
    float* QKVG = ws;                          // M*1280  (reused later as H2: M*1024)
    float* H1   = QKVG + (size_t)M_*1280;      // M*512   (aliased as scan-carry space)
    float* BUF2 = H1   + (size_t)M_*512;
    float* BUF3 = BUF2 + (size_t)M_*256;
    float* BUF4 = BUF3 + (size_t)M_*256;
    float* BUF5 = BUF4 + (size_t)M_*256;       // VT (steps 1-4) -> CONC -> PR
    float* BUF6 = BUF5 + (size_t)M_*256;
    float* H2   = QKVG;
    float* VT   = BUF5;                        // V^T [b][h][d][t], live steps 1-4

    float* CAR0 = H1;
    float* CAR1 = H1 + (size_t)B_*NC_*D_;

    float* out_pr = (float*)d_out;
    float* out_fs = out_pr + (size_t)M_*256;
    float* out_tj = out_fs + B_*256;

    const dim3 blk256(256);
    const dim3 scan_grid(NC_, B_);
    const int NR = M_/64;   // 128 row tiles

    // 1. qkv projection -> QKVG[:, 0:768) (+ V^T side write)
    gemm_k<<<dim3(NR*12), blk256, 0, stream>>>(
        X, qkv_w, 256, 256,  nullptr,nullptr,0,0,  nullptr,nullptr,0,0,
        qkv_b, nullptr, QKVG, 1280, OP_NONE, 12, VT);
    // 2. gkv projection -> QKVG[:, 768:1280)
    gemm_k<<<dim3(NR*8), blk256, 0, stream>>>(
        X, gkv_w, 256, 256,  nullptr,nullptr,0,0,  nullptr,nullptr,0,0,
        gkv_b, nullptr, QKVG+768, 1280, OP_NONE, 8, nullptr);
    // 3. local_history (depthwise conv) -> BUF2
    conv_k<<<dim3(M_*D_/256), blk256, 0, stream>>>(X, conv_w, conv_b, BUF2);
    // 4. banded attention (MFMA) -> BUF3
    attn_k<<<dim3(T_/64, H_, B_), blk256, 0, stream>>>(QKVG, VT, BUF3);
    // 5. mo projection -> BUF4
    gemm_k<<<dim3(NR*4), blk256, 0, stream>>>(
        BUF3, mo_w, 256, 256,  nullptr,nullptr,0,0,  nullptr,nullptr,0,0,
        mo_b, nullptr, BUF4, 256, OP_NONE, 4, nullptr);
    // 6. concepts scan (chunked) -> BUF5
    scan1_p1<<<scan_grid, blk256, 0, stream>>>(QKVG, CAR0, CAR1);
    scan1_p2<<<dim3(4), blk256, 0, stream>>>(CAR0, CAR1);
    scan1_p3<<<scan_grid, blk256, 0, stream>>>(QKVG, CAR0, CAR1, BUF5);
    // 7. global_out -> BUF6
    gemm_k<<<dim3(NR*4), blk256, 0, stream>>>(
        BUF5, go_w, 256, 256,  nullptr,nullptr,0,0,  nullptr,nullptr,0,0,
        go_b, nullptr, BUF6, 256, OP_NONE, 4, nullptr);
    // 8. medium_out = MED2 * sigmoid([X,MED2]@fg^T + b) -> BUF3
    gemm_k<<<dim3(NR*4), blk256, 0, stream>>>(
        X, fg_w, 512, 256,  BUF4, fg_w+256, 512, 256,  nullptr,nullptr,0,0,
        fg_b, BUF4, BUF3, 256, OP_SIGMUL, 4, nullptr);
    // 9. pre_ln1 = X + [LH,MOUT,GOUT]@comb^T + b -> BUF4
    gemm_k<<<dim3(NR*4), blk256, 0, stream>>>(
        BUF2, comb_w, 768, 256,  BUF3, comb_w+256, 768, 256,  BUF6, comb_w+512, 768, 256,
        comb_b, X, BUF4, 256, OP_ADDAUX, 4, nullptr);
    // 10. pr = LN1 -> BUF5
    ln_k<<<dim3(M_/4), blk256, 0, stream>>>(BUF4, ln1_g, ln1_b, BUF5);
    // 11. global_summary EMA -> BUF6, final_traj -> out
    ema_p1<<<scan_grid, blk256, 0, stream>>>(BUF5, CAR0, 0.1f);
    ema_p2<<<dim3(4), blk256, 0, stream>>>(CAR0, out_tj);
    ema_p3<<<scan_grid, blk256, 0, stream>>>(BUF5, CAR0, BUF6, 0.1f);
    // 12. cs1 = pr + 0.3*(pr@p2s^T + b) -> BUF2
    gemm_k<<<dim3(NR*4), blk256, 0, stream>>>(
        BUF5, p2s_w, 256, 256,  nullptr,nullptr,0,0,  nullptr,nullptr,0,0,
        p2s_b, BUF5, BUF2, 256, OP_AXPBY, 4, nullptr);
    // 13. H1 = gelu(cs1@tr1a + gsum@tr1b + b)
    gemm_k<<<dim3(NR*8), blk256, 0, stream>>>(
        BUF2, tr1_w, 512, 256,  BUF6, tr1_w+256, 512, 256,  nullptr,nullptr,0,0,
        tr1_b, nullptr, H1, 512, OP_GELU, 8, nullptr);
    // 14. scaled = 0.5*tanh(H1@tr2^T + b) -> BUF3
    gemm_k<<<dim3(NR*4), blk256, 0, stream>>>(
        H1, tr2_w, 512, 512,  nullptr,nullptr,0,0,  nullptr,nullptr,0,0,
        tr2_b, nullptr, BUF3, 256, OP_TANHHALF, 4, nullptr);
    // 15. state EMA + decayed initial -> BUF4 (pre_ln3)
    ema_p1<<<scan_grid, blk256, 0, stream>>>(BUF3, CAR0, 1.0f);
    ema_p2<<<dim3(4), blk256, 0, stream>>>(CAR0, nullptr);
    ema_p3_state<<<scan_grid, blk256, 0, stream>>>(BUF3, CAR0, SEQ, BUF4);
    // 16. states = LN3 -> BUF6; final_state = LN4(states[-1]) -> out
    ln3_k<<<dim3(M_/4), blk256, 0, stream>>>(BUF4, ln3_g, ln3_b, BUF6, ln4_g, ln4_b, out_fs);
    // 17. ffn_in = pr + 0.3*(states@s2p^T + b) -> BUF2
    gemm_k<<<dim3(NR*4), blk256, 0, stream>>>(
        BUF6, s2p_w, 256, 256,  nullptr,nullptr,0,0,  nullptr,nullptr,0,0,
        s2p_b, BUF5, BUF2, 256, OP_AXPBY, 4, nullptr);
    // 18. H2 = gelu(ffn_in@ffn1^T + b)
    gemm_k<<<dim3(NR*16), blk256, 0, stream>>>(
        BUF2, ffn1_w, 256, 256,  nullptr,nullptr,0,0,  nullptr,nullptr,0,0,
        ffn1_b, nullptr, H2, 1024, OP_GELU, 16, nullptr);
    // 19. pre_ln2 = pr + H2@ffn2^T + b -> BUF3
    gemm_k<<<dim3(NR*4), blk256, 0, stream>>>(
        H2, ffn2_w, 1024, 1024,  nullptr,nullptr,0,0,  nullptr,nullptr,0,0,
        ffn2_b, BUF5, BUF3, 256, OP_ADDAUX, 4, nullptr);
    // 20. pr_out = LN2 -> d_out
    ln_k<<<dim3(M_/4), blk256, 0, stream>>>(BUF3, ln2_g, ln2_b, out_pr);
}

// Round 6
// 255.755 us; speedup vs baseline: 4.3481x; 1.0761x over previous
//
#include <hip/hip_runtime.h>
#include <hip/hip_bf16.h>
#include <math.h>

#define D_  256
#define T_  2048
#define B_  4
#define M_  (B_*T_)
#define H_  4
#define HD_ 64

#define NC_ 64          // scan chunks
#define LCH (T_/NC_)    // 32 steps per chunk

enum { OP_NONE=0, OP_SIGMUL=1, OP_ADDAUX=2, OP_AXPBY=3, OP_GELU=4, OP_TANHHALF=5 };

typedef unsigned short u16;
typedef short short8 __attribute__((ext_vector_type(8)));
typedef float f32x4  __attribute__((ext_vector_type(4)));

__device__ __forceinline__ float gelu_f(float x){ return 0.5f*x*(1.0f+erff(x*0.70710678118654752f)); }
__device__ __forceinline__ float sigmoid_f(float x){ return 1.0f/(1.0f+expf(-x)); }

// pack 2 fp32 -> 2 bf16 (RNE) in one uint (low u16 = a, high = b)
__device__ __forceinline__ unsigned pk2(float a, float b){
    __hip_bfloat162 h = __float22bfloat162_rn(make_float2(a,b));
    union { __hip_bfloat162 h; unsigned u; } c; c.h = h; return c.u;
}
__device__ __forceinline__ float bfu(u16 u){ return __uint_as_float(((unsigned)u)<<16); }
__device__ __forceinline__ u16 bf1(float x){ return (u16)(pk2(x,x)&0xffffu); }

// weight-pack element offsets inside Wh (u16 elements)
#define OFF_QKV   0u        // fused qkv(768)+gkv(512) rows -> [1280,256]
#define OFF_MO    327680u
#define OFF_FG    393216u
#define OFF_GO    524288u
#define OFF_COMB  589824u
#define OFF_FFN1  786432u
#define OFF_FFN2  1048576u
#define OFF_TR1   1310720u
#define OFF_TR2   1572864u
#define OFF_P2S   1703936u
#define OFF_S2P   1769472u
#define NWELEM    1835008u
#define NXELEM    2097152u

// ---------------------------------------------------------------------------
// One-shot fp32 -> bf16 conversion of all weights + X, and qkv/gkv bias concat.
// ---------------------------------------------------------------------------
__global__ __launch_bounds__(256) void cvt_k(
    const float* __restrict__ qkv_w, const float* __restrict__ gkv_w,
    const float* __restrict__ qkv_b, const float* __restrict__ gkv_b,
    const float* __restrict__ mo_w,  const float* __restrict__ fg_w,
    const float* __restrict__ go_w,  const float* __restrict__ comb_w,
    const float* __restrict__ ffn1_w,const float* __restrict__ ffn2_w,
    const float* __restrict__ tr1_w, const float* __restrict__ tr2_w,
    const float* __restrict__ p2s_w, const float* __restrict__ s2p_w,
    const float* __restrict__ X,
    u16* __restrict__ Wh, u16* __restrict__ Xh, float* __restrict__ bq)
{
    size_t i = ((size_t)blockIdx.x*256 + threadIdx.x)*4;
    if (i < NWELEM){
        const float* s; size_t base;
        if      (i < OFF_MO)  { s=(i<196608)?qkv_w:gkv_w; base=(i<196608)?0:196608; }
        else if (i < OFF_FG)  { s=mo_w;   base=OFF_MO; }
        else if (i < OFF_GO)  { s=fg_w;   base=OFF_FG; }
        else if (i < OFF_COMB){ s=go_w;   base=OFF_GO; }
        else if (i < OFF_FFN1){ s=comb_w; base=OFF_COMB; }
        else if (i < OFF_FFN2){ s=ffn1_w; base=OFF_FFN1; }
        else if (i < OFF_TR1) { s=ffn2_w; base=OFF_FFN2; }
        else if (i < OFF_TR2) { s=tr1_w;  base=OFF_TR1; }
        else if (i < OFF_P2S) { s=tr2_w;  base=OFF_TR2; }
        else if (i < OFF_S2P) { s=p2s_w;  base=OFF_P2S; }
        else                  { s=s2p_w;  base=OFF_S2P; }
        float4 v = *(const float4*)(s + (i-base));
        *(uint2*)(Wh + i) = (uint2){ pk2(v.x,v.y), pk2(v.z,v.w) };
    } else if (i < NWELEM + NXELEM){
        size_t j = i - NWELEM;
        float4 v = *(const float4*)(X + j);
        *(uint2*)(Xh + j) = (uint2){ pk2(v.x,v.y), pk2(v.z,v.w) };
    } else if (i < NWELEM + NXELEM + 1280){
        size_t j = i - (NWELEM + NXELEM);
        #pragma unroll
        for (int k=0;k<4;++k){
            size_t e = j + k;
            bq[e] = (e < 768) ? qkv_b[e] : gkv_b[e-768];
        }
    }
}

// ---------------------------------------------------------------------------
// bf16 MFMA GEMM, register-staged pipeline, all-bf16 A/W inputs.
// Tile 64x64, BK=64, 4 waves (2x2), mfma_f32_16x16x32_bf16, XCD swizzle.
// ---------------------------------------------------------------------------
__global__ __launch_bounds__(256) void gemm_k(
    const u16* __restrict__ A0, const u16* __restrict__ W0, int ldw0, int K0,
    const u16* __restrict__ A1, const u16* __restrict__ W1, int ldw1, int K1,
    const u16* __restrict__ A2, const u16* __restrict__ W2, int ldw2, int K2,
    const float* __restrict__ bias, const void* __restrict__ aux, int aux_bf16,
    void* __restrict__ C, int ldc, int c_bf16, int op, int ncol, u16* __restrict__ vt)
{
    __shared__ u16 As[64*64];
    __shared__ u16 Ws[64*64];

    const int q8   = gridDim.x >> 3;
    const int lid  = (blockIdx.x & 7)*q8 + (blockIdx.x >> 3);
    const int brow = lid / ncol;
    const int bcol = lid - brow*ncol;
    const int row0 = brow*64, col0 = bcol*64;

    const int tid  = threadIdx.x;
    const int lane = tid & 63, wid = tid >> 6;
    const int wm = (wid >> 1)*32, wn = (wid & 1)*32;
    const int l15 = lane & 15, l4 = lane >> 4;
    const int srow = tid >> 3;          // 0..31
    const int sc8  = (tid & 7) * 8;

    f32x4 acc[2][2];
    #pragma unroll
    for (int i=0;i<2;++i)
        #pragma unroll
        for (int j=0;j<2;++j) acc[i][j] = (f32x4){0.f,0.f,0.f,0.f};

    uint4 ra0, ra1, rw0, rw1;

    auto loadtile = [&](const u16* A, const u16* W, int ldw, int K, int kb){
        const u16* ga = A + (size_t)(row0+srow)*K + kb + sc8;
        ra0 = *(const uint4*)ga;
        ra1 = *(const uint4*)(ga + (size_t)32*K);
        const u16* gw = W + (size_t)(col0+srow)*ldw + kb + sc8;
        rw0 = *(const uint4*)gw;
        rw1 = *(const uint4*)(gw + (size_t)32*ldw);
    };
    auto storetile = [&](){
        const int i0 = (srow*64 + sc8) ^ ((srow&7)<<3);
        *(uint4*)&As[i0] = ra0;  *(uint4*)&Ws[i0] = rw0;
        const int r2 = srow + 32;
        const int i1 = (r2*64 + sc8) ^ ((r2&7)<<3);
        *(uint4*)&As[i1] = ra1;  *(uint4*)&Ws[i1] = rw1;
    };
    auto mfma_tile = [&](){
        #pragma unroll
        for (int ks=0;ks<2;++ks){
            const int koff = ks*32 + l4*8;
            short8 af[2], bf[2];
            #pragma unroll
            for (int f=0;f<2;++f){
                const int ar = wm + f*16 + l15;
                af[f] = *(const short8*)&As[(ar*64 + koff) ^ ((ar&7)<<3)];
                const int brn = wn + f*16 + l15;
                bf[f] = *(const short8*)&Ws[(brn*64 + koff) ^ ((brn&7)<<3)];
            }
            #pragma unroll
            for (int fm=0;fm<2;++fm)
                #pragma unroll
                for (int fn=0;fn<2;++fn)
                    acc[fm][fn] = __builtin_amdgcn_mfma_f32_16x16x32_bf16(
                        af[fm], bf[fn], acc[fm][fn], 0, 0, 0);
        }
    };

    const u16* Ac = A0; const u16* Wc = W0; int ldwc = ldw0, Kc = K0, kb = 0;
    loadtile(Ac, Wc, ldwc, Kc, 0);
    while (true){
        __syncthreads();            // drains in-flight loads + LDS free
        storetile();
        __syncthreads();            // staged tile visible
        int nkb = kb + 64;
        const u16* nA = Ac; const u16* nW = Wc; int nld = ldwc, nK = Kc;
        bool have_next = true;
        if (nkb >= Kc){
            if (Ac == A0 && A1){ nA = A1; nW = W1; nld = ldw1; nK = K1; nkb = 0; }
            else if (Ac == A1 && A2){ nA = A2; nW = W2; nld = ldw2; nK = K2; nkb = 0; }
            else have_next = false;
        }
        if (have_next) loadtile(nA, nW, nld, nK, nkb);   // in flight across MFMA
        mfma_tile();
        if (!have_next) break;
        Ac = nA; Wc = nW; ldwc = nld; Kc = nK; kb = nkb;
    }

    #pragma unroll
    for (int fn=0;fn<2;++fn){
        const int n = col0 + wn + fn*16 + l15;
        const float bv = bias[n];
        const bool vwr = (vt != nullptr) && (n >= 512) && (n < 768);
        #pragma unroll
        for (int fm=0;fm<2;++fm){
            #pragma unroll
            for (int j=0;j<4;++j){
                const int m = row0 + wm + fm*16 + l4*4 + j;
                float v = acc[fm][fn][j] + bv;
                if (op==OP_GELU)          v = gelu_f(v);
                else if (op==OP_TANHHALF) v = 0.5f*tanhf(v);
                else if (op!=OP_NONE){
                    const size_t ai = (size_t)m*D_ + n;
                    const float a = aux_bf16 ? bfu(((const u16*)aux)[ai])
                                             : ((const float*)aux)[ai];
                    if (op==OP_SIGMUL)      v = a*sigmoid_f(v);
                    else if (op==OP_ADDAUX) v = v + a;
                    else                    v = a + 0.3f*v;
                }
                if (c_bf16) ((u16*)C)[(size_t)m*ldc + n] = bf1(v);
                else        ((float*)C)[(size_t)m*ldc + n] = v;
                if (vwr){
                    const int hh = (n-512)>>6, dd = (n-512)&63;
                    const int bb = m >> 11, tt = m & (T_-1);
                    vt[(((size_t)(bb*H_ + hh))*64 + dd)*T_ + tt] = bf1(v);
                }
            }
        }
    }
}

// ---------------------------------------------------------------------------
// Depthwise causal conv, K=8, pad left 7. fp32 in, bf16 out.
// ---------------------------------------------------------------------------
__global__ __launch_bounds__(256) void conv_k(const float* __restrict__ X,
    const float* __restrict__ w, const float* __restrict__ bias, u16* __restrict__ out)
{
    int idx = blockIdx.x*256 + threadIdx.x;
    int d = idx & (D_-1);
    int bt = idx >> 8;
    int t = bt & (T_-1);
    float acc = bias[d];
    const float* xp = X + (size_t)bt*D_ + d;
    const float* wp = w + d*8;
    #pragma unroll
    for (int j=0;j<8;++j){
        int tt = t - 7 + j;
        if (tt >= 0) acc += xp[(size_t)(j-7)*D_] * wp[j];
    }
    out[idx] = bf1(acc);
}

// ---------------------------------------------------------------------------
// MFMA banded attention, all-bf16 inputs. Per block: (b, h, 64-query tile).
// ---------------------------------------------------------------------------
__global__ __launch_bounds__(256) void attn_k(const u16* __restrict__ QKVG,
    const u16* __restrict__ VT, u16* __restrict__ MED)
{
    __shared__ u16 Kl[128*64];
    __shared__ u16 Ql[64*64];
    __shared__ u16 Vl[64*128];
    const int b = blockIdx.z, h = blockIdx.y;
    const int t0 = blockIdx.x * 64;
    const int kb0 = t0 - 64;
    const int tid = threadIdx.x;

    {   // stage K (128 key rows x 64 dims) and Q (64 rows)
        const int r0 = tid >> 3, c8 = (tid & 7) * 8;
        #pragma unroll
        for (int rep=0;rep<4;++rep){
            const int r = r0 + rep*32;
            const int kg = kb0 + r;
            uint4 pk = {0,0,0,0};
            if (kg >= 0)
                pk = *(const uint4*)(QKVG + ((size_t)(b*T_ + kg))*1280 + 256 + h*HD_ + c8);
            *(uint4*)&Kl[(r*64 + c8) ^ ((r&7)<<3)] = pk;
        }
        #pragma unroll
        for (int rep=0;rep<2;++rep){
            const int r = r0 + rep*32;
            uint4 pq = *(const uint4*)(QKVG + ((size_t)(b*T_ + t0 + r))*1280 + h*HD_ + c8);
            *(uint4*)&Ql[(r*64 + c8) ^ ((r&7)<<3)] = pq;
        }
    }
    {   // stage VT (64 dims x 128 keys)
        const int d0 = tid >> 4, c8 = (tid & 15) * 8;
        #pragma unroll
        for (int rep=0;rep<4;++rep){
            const int d = d0 + rep*16;
            uint4 pv = {0,0,0,0};
            if (kb0 + c8 >= 0)
                pv = *(const uint4*)(VT + ((size_t)((b*H_ + h)*64 + d))*T_ + kb0 + c8);
            *(uint4*)&Vl[(d*128 + c8) ^ ((d&7)<<3)] = pv;
        }
    }
    __syncthreads();

    const int lane = tid & 63, w = tid >> 6;
    const int l15 = lane & 15, l4 = lane >> 4;

    short8 bq[2];
    {
        const int qr = w*16 + l15;
        bq[0] = *(const short8*)&Ql[(qr*64 +      l4*8) ^ ((qr&7)<<3)];
        bq[1] = *(const short8*)&Ql[(qr*64 + 32 + l4*8) ^ ((qr&7)<<3)];
    }

    f32x4 s[8];
    #pragma unroll
    for (int kf=0;kf<8;++kf){
        const int kr = kf*16 + l15;
        short8 a0 = *(const short8*)&Kl[(kr*64 +      l4*8) ^ ((kr&7)<<3)];
        short8 a1 = *(const short8*)&Kl[(kr*64 + 32 + l4*8) ^ ((kr&7)<<3)];
        f32x4 acc = (f32x4){0.f,0.f,0.f,0.f};
        acc = __builtin_amdgcn_mfma_f32_16x16x32_bf16(a0, bq[0], acc, 0,0,0);
        acc = __builtin_amdgcn_mfma_f32_16x16x32_bf16(a1, bq[1], acc, 0,0,0);
        s[kf] = acc;
    }

    const int qg = t0 + w*16 + l15;
    float m = -1e30f;
    #pragma unroll
    for (int kf=0;kf<8;++kf){
        #pragma unroll
        for (int j=0;j<4;++j){
            const int kg = kb0 + kf*16 + l4*4 + j;
            const int diff = qg - kg;
            const float v = (kg >= 0 && diff >= 0 && diff < 64) ? s[kf][j]*0.125f : -1e30f;
            s[kf][j] = v;
            m = fmaxf(m, v);
        }
    }
    m = fmaxf(m, __shfl_xor(m,16));
    m = fmaxf(m, __shfl_xor(m,32));
    float lsum = 0.f;
    unsigned lo[8], hi[8];
    #pragma unroll
    for (int kf=0;kf<8;++kf){
        const float p0 = expf(s[kf][0]-m), p1 = expf(s[kf][1]-m);
        const float p2 = expf(s[kf][2]-m), p3 = expf(s[kf][3]-m);
        lsum += (p0+p1)+(p2+p3);
        lo[kf] = pk2(p0,p1);
        hi[kf] = pk2(p2,p3);
    }
    lsum += __shfl_xor(lsum,16);
    lsum += __shfl_xor(lsum,32);
    const float inv = 1.f/lsum;

    f32x4 o[4];
    #pragma unroll
    for (int df=0;df<4;++df) o[df] = (f32x4){0.f,0.f,0.f,0.f};
    const int baseLane = l15 + ((l4&1)<<5);
    const bool hiHalf = (l4>>1) != 0;
    #pragma unroll
    for (int kb=0;kb<4;++kb){
        const int x0 = __shfl((int)lo[2*kb],   baseLane);
        const int x1 = __shfl((int)hi[2*kb],   baseLane);
        const int x2 = __shfl((int)lo[2*kb],   baseLane+16);
        const int x3 = __shfl((int)hi[2*kb],   baseLane+16);
        const int y0 = __shfl((int)lo[2*kb+1], baseLane);
        const int y1 = __shfl((int)hi[2*kb+1], baseLane);
        const int y2 = __shfl((int)lo[2*kb+1], baseLane+16);
        const int y3 = __shfl((int)hi[2*kb+1], baseLane+16);
        int4 afi;
        afi.x = hiHalf ? y0 : x0;
        afi.y = hiHalf ? y1 : x1;
        afi.z = hiHalf ? y2 : x2;
        afi.w = hiHalf ? y3 : x3;
        union { int4 i; short8 s; } cv; cv.i = afi;
        #pragma unroll
        for (int df=0;df<4;++df){
            const int vr = df*16 + l15;
            short8 bv = *(const short8*)&Vl[(vr*128 + kb*32 + l4*8) ^ ((vr&7)<<3)];
            o[df] = __builtin_amdgcn_mfma_f32_16x16x32_bf16(cv.s, bv, o[df], 0,0,0);
        }
    }

    #pragma unroll
    for (int j=0;j<4;++j){
        const float invj = __shfl(inv, l4*4 + j);
        const int mrow = b*T_ + t0 + w*16 + l4*4 + j;
        u16* op = MED + (size_t)mrow*D_ + h*HD_ + l15;
        #pragma unroll
        for (int df=0;df<4;++df)
            op[df*16] = bf1(o[df][j] * invj);
    }
}

// ---------------------------------------------------------------------------
// Chunked parallel scans.
// ---------------------------------------------------------------------------
__global__ __launch_bounds__(256) void scan1_p1(const u16* __restrict__ QKVG,
    float* __restrict__ CA, float* __restrict__ CC)
{
    const int d = threadIdx.x, c = blockIdx.x, b = blockIdx.y;
    const u16* base = QKVG + ((size_t)(b*T_ + c*LCH))*1280;
    float sgk=0.f, sgkv=0.f;
    for (int t=0;t<LCH;++t){
        float gk = bfu(base[(size_t)t*1280 + 768 + d]);
        gk = gk > 0.f ? gk + 1.f : expf(gk);
        float gv = bfu(base[(size_t)t*1280 + 1024 + d]);
        sgk += gk; sgkv += gk*gv;
    }
    CA[((size_t)b*NC_ + c)*D_ + d] = sgk;
    CC[((size_t)b*NC_ + c)*D_ + d] = sgkv;
}

__global__ void scan1_p2(float* __restrict__ CA, float* __restrict__ CC)
{
    int idx = blockIdx.x*256 + threadIdx.x;
    int d = idx & (D_-1), b = idx >> 8;
    float sa=0.f, sc=0.f;
    for (int c=0;c<NC_;++c){
        size_t o = ((size_t)b*NC_ + c)*D_ + d;
        float a = CA[o], cc = CC[o];
        CA[o] = sa; CC[o] = sc;
        sa += a; sc += cc;
    }
}

__global__ __launch_bounds__(256) void scan1_p3(const u16* __restrict__ QKVG,
    const float* __restrict__ CA, const float* __restrict__ CC, u16* __restrict__ CONC)
{
    const int d = threadIdx.x, c = blockIdx.x, b = blockIdx.y;
    float sgk  = CA[((size_t)b*NC_ + c)*D_ + d];
    float sgkv = CC[((size_t)b*NC_ + c)*D_ + d];
    const u16* base = QKVG + ((size_t)(b*T_ + c*LCH))*1280;
    u16* out = CONC + ((size_t)(b*T_ + c*LCH))*D_ + d;
    for (int t=0;t<LCH;++t){
        float gk = bfu(base[(size_t)t*1280 + 768 + d]);
        gk = gk > 0.f ? gk + 1.f : expf(gk);
        float gv = bfu(base[(size_t)t*1280 + 1024 + d]);
        sgk += gk; sgkv += gk*gv;
        out[(size_t)t*D_] = bf1(sgkv / (sgk + 1e-5f));
    }
}

__global__ __launch_bounds__(256) void ema_p1(const float* __restrict__ X,
    float* __restrict__ CARRY, float alpha)
{
    const int d = threadIdx.x, c = blockIdx.x, b = blockIdx.y;
    const float* xp = X + ((size_t)(b*T_ + c*LCH))*D_ + d;
    float g = 0.f;
    for (int t=0;t<LCH;++t) g = 0.9f*g + alpha*xp[(size_t)t*D_];
    CARRY[((size_t)b*NC_ + c)*D_ + d] = g;
}

__global__ void ema_p2(float* __restrict__ CARRY, float* __restrict__ traj)
{
    int idx = blockIdx.x*256 + threadIdx.x;
    int d = idx & (D_-1), b = idx >> 8;
    const float dL = powf(0.9f, (float)LCH);
    float run = 0.f;
    for (int c=0;c<NC_;++c){
        size_t o = ((size_t)b*NC_ + c)*D_ + d;
        float loc = CARRY[o];
        CARRY[o] = run;
        run = loc + dL*run;
    }
    if (traj) traj[b*D_ + d] = run;
}

// EMA replay writing bf16 (for GSUM -> tr1 input)
__global__ __launch_bounds__(256) void ema_p3h(const float* __restrict__ X,
    const float* __restrict__ CARRY, u16* __restrict__ OUT, float alpha)
{
    const int d = threadIdx.x, c = blockIdx.x, b = blockIdx.y;
    float g = CARRY[((size_t)b*NC_ + c)*D_ + d];
    const float* xp = X + ((size_t)(b*T_ + c*LCH))*D_ + d;
    u16* op = OUT + ((size_t)(b*T_ + c*LCH))*D_ + d;
    for (int t=0;t<LCH;++t){
        g = 0.9f*g + alpha*xp[(size_t)t*D_];
        op[(size_t)t*D_] = bf1(g);
    }
}

__global__ __launch_bounds__(256) void ema_p3_state(const float* __restrict__ X,
    const float* __restrict__ CARRY, const float* __restrict__ SEQ, float* __restrict__ OUT)
{
    const int d = threadIdx.x, c = blockIdx.x, b = blockIdx.y;
    float a = CARRY[((size_t)b*NC_ + c)*D_ + d];
    const float ss = SEQ[b*D_ + d];
    float dp = powf(0.9f, (float)(c*LCH + 1));
    const float* xp = X + ((size_t)(b*T_ + c*LCH))*D_ + d;
    float* op = OUT + ((size_t)(b*T_ + c*LCH))*D_ + d;
    for (int t=0;t<LCH;++t){
        a = 0.9f*a + xp[(size_t)t*D_];
        op[(size_t)t*D_] = fmaf(ss, dp, a);
        dp *= 0.9f;
    }
}

// ---------------------------------------------------------------------------
// LayerNorms
// ---------------------------------------------------------------------------
__global__ __launch_bounds__(256) void ln_k(const float* __restrict__ in,
    const float* __restrict__ g, const float* __restrict__ b,
    float* __restrict__ out, u16* __restrict__ out2)
{
    int row  = blockIdx.x*4 + (threadIdx.x>>6);
    int lane = threadIdx.x & 63;
    const float* ip = in + (size_t)row*D_ + lane*4;
    float4 x = *(const float4*)ip;
    float s  = x.x+x.y+x.z+x.w;
    float s2 = x.x*x.x + x.y*x.y + x.z*x.z + x.w*x.w;
    #pragma unroll
    for (int o=1;o<64;o<<=1){ s += __shfl_xor(s,o); s2 += __shfl_xor(s2,o); }
    float mean = s * (1.f/256.f);
    float var  = s2 * (1.f/256.f) - mean*mean;
    float rs = rsqrtf(var + 1e-5f);
    int db = lane*4;
    float4 r;
    r.x=(x.x-mean)*rs*g[db+0]+b[db+0];
    r.y=(x.y-mean)*rs*g[db+1]+b[db+1];
    r.z=(x.z-mean)*rs*g[db+2]+b[db+2];
    r.w=(x.w-mean)*rs*g[db+3]+b[db+3];
    *(float4*)(out + (size_t)row*D_ + db) = r;
    if (out2)
        *(uint2*)(out2 + (size_t)row*D_ + db) = (uint2){ pk2(r.x,r.y), pk2(r.z,r.w) };
}

// LN3 (states, bf16 out) + LN4 on the last timestep row -> final_state (fp32)
__global__ __launch_bounds__(256) void ln3_k(const float* __restrict__ in,
    const float* __restrict__ g3, const float* __restrict__ b3, u16* __restrict__ states,
    const float* __restrict__ g4, const float* __restrict__ b4, float* __restrict__ fsout)
{
    int row  = blockIdx.x*4 + (threadIdx.x>>6);
    int lane = threadIdx.x & 63;
    const float* ip = in + (size_t)row*D_ + lane*4;
    float4 x = *(const float4*)ip;
    float s  = x.x+x.y+x.z+x.w;
    float s2 = x.x*x.x + x.y*x.y + x.z*x.z + x.w*x.w;
    #pragma unroll
    for (int o=1;o<64;o<<=1){ s += __shfl_xor(s,o); s2 += __shfl_xor(s2,o); }
    float mean = s * (1.f/256.f);
    float var  = s2 * (1.f/256.f) - mean*mean;
    float rs = rsqrtf(var + 1e-5f);
    int db = lane*4;
    float4 st;
    st.x=(x.x-mean)*rs*g3[db+0]+b3[db+0];
    st.y=(x.y-mean)*rs*g3[db+1]+b3[db+1];
    st.z=(x.z-mean)*rs*g3[db+2]+b3[db+2];
    st.w=(x.w-mean)*rs*g3[db+3]+b3[db+3];
    *(uint2*)(states + (size_t)row*D_ + db) = (uint2){ pk2(st.x,st.y), pk2(st.z,st.w) };

    if ((row & (T_-1)) == T_-1){
        float u  = st.x+st.y+st.z+st.w;
        float u2 = st.x*st.x + st.y*st.y + st.z*st.z + st.w*st.w;
        #pragma unroll
        for (int o=1;o<64;o<<=1){ u += __shfl_xor(u,o); u2 += __shfl_xor(u2,o); }
        float m2 = u * (1.f/256.f);
        float v2 = u2 * (1.f/256.f) - m2*m2;
        float r2 = rsqrtf(v2 + 1e-5f);
        float4 fs;
        fs.x=(st.x-m2)*r2*g4[db+0]+b4[db+0];
        fs.y=(st.y-m2)*r2*g4[db+1]+b4[db+1];
        fs.z=(st.z-m2)*r2*g4[db+2]+b4[db+2];
        fs.w=(st.w-m2)*r2*g4[db+3]+b4[db+3];
        *(float4*)(fsout + (size_t)(row>>11)*D_ + db) = fs;
    }
}

// ---------------------------------------------------------------------------
extern "C" void kernel_launch(void* const* d_in, const int* in_sizes, int n_in,
                              void* d_out, int out_size, void* d_ws, size_t ws_size,
                              hipStream_t stream)
{
    const float* X     = (const float*)d_in[0];
    const float* SEQ   = (const float*)d_in[1];
    const float* conv_w= (const float*)d_in[3];
    const float* conv_b= (const float*)d_in[4];
    const float* qkv_w = (const float*)d_in[5];
    const float* qkv_b = (const float*)d_in[6];
    const float* mo_w  = (const float*)d_in[7];
    const float* mo_b  = (const float*)d_in[8];
    const float* fg_w  = (const float*)d_in[9];
    const float* fg_b  = (const float*)d_in[10];
    const float* gkv_w = (const float*)d_in[11];
    const float* gkv_b = (const float*)d_in[12];
    const float* go_w  = (const float*)d_in[13];
    const float* go_b  = (const float*)d_in[14];
    const float* comb_w= (const float*)d_in[15];
    const float* comb_b= (const float*)d_in[16];
    const float* ffn1_w= (const float*)d_in[17];
    const float* ffn1_b= (const float*)d_in[18];
    const float* ffn2_w= (const float*)d_in[19];
    const float* ffn2_b= (const float*)d_in[20];
    const float* tr1_w = (const float*)d_in[21];
    const float* tr1_b = (const float*)d_in[22];
    const float* tr2_w = (const float*)d_in[23];
    const float* tr2_b = (const float*)d_in[24];
    const float* p2s_w = (const float*)d_in[25];
    const float* p2s_b = (const float*)d_in[26];
    const float* s2p_w = (const float*)d_in[27];
    const float* s2p_b = (const float*)d_in[28];
    const float* ln1_g = (const float*)d_in[29];
    const float* ln1_b = (const float*)d_in[30];
    const float* ln2_g = (const float*)d_in[31];
    const float* ln2_b = (const float*)d_in[32];
    const float* ln3_g = (const float*)d_in[33];
    const float* ln3_b = (const float*)d_in[34];
    const float* ln4_g = (const float*)d_in[35];
    const float* ln4_b = (const float*)d_in[36];

    // -------- workspace carve (256-byte aligned chunks) --------
    char* p = (char*)d_ws;
    auto alloc = [&](size_t bytes)->char*{ char* r = p; p += (bytes + 255) & ~(size_t)255; return r; };

    u16*   QKVG = (u16*)  alloc((size_t)M_*1280*2);
    u16*   Wh   = (u16*)  alloc((size_t)NWELEM*2);
    float* bq   = (float*)alloc(1280*4);
    u16*   Xh   = (u16*)  alloc((size_t)M_*256*2);
    u16*   VTh  = (u16*)  alloc((size_t)M_*256*2);
    u16*   MED  = (u16*)  alloc((size_t)M_*256*2);
    u16*   MED2 = (u16*)  alloc((size_t)M_*256*2);
    u16*   LH   = (u16*)  alloc((size_t)M_*256*2);
    u16*   CONC = (u16*)  alloc((size_t)M_*256*2);
    u16*   GOUT = (u16*)  alloc((size_t)M_*256*2);
    u16*   MOUT = (u16*)  alloc((size_t)M_*256*2);
    float* PRE1 = (float*)alloc((size_t)M_*256*4);
    float* PR   = (float*)alloc((size_t)M_*256*4);
    u16*   PRh  = (u16*)  alloc((size_t)M_*256*2);
    u16*   GSUM = (u16*)  alloc((size_t)M_*256*2);
    u16*   CS1  = (u16*)  alloc((size_t)M_*256*2);
    u16*   H1   = (u16*)  alloc((size_t)M_*512*2);
    float* SCALED=(float*)alloc((size_t)M_*256*4);
    float* PRE3 = (float*)alloc((size_t)M_*256*4);
    u16*   STATESh=(u16*) alloc((size_t)M_*256*2);
    u16*   FFNIN= (u16*)  alloc((size_t)M_*256*2);
    u16*   H2   = (u16*)  alloc((size_t)M_*1024*2);
    float* PRE2 = (float*)alloc((size_t)M_*256*4);
    float* CAR0 = (float*)alloc((size_t)B_*NC_*D_*4);
    float* CAR1 = (float*)alloc((size_t)B_*NC_*D_*4);

    float* out_pr = (float*)d_out;
    float* out_fs = out_pr + (size_t)M_*256;
    float* out_tj = out_fs + B_*256;

    const dim3 blk256(256);
    const dim3 scan_grid(NC_, B_);
    const int NR = M_/64;   // 128 row tiles

    // 0. convert weights + X to bf16, concat qkv/gkv bias
    cvt_k<<<dim3(3842), blk256, 0, stream>>>(
        qkv_w, gkv_w, qkv_b, gkv_b, mo_w, fg_w, go_w, comb_w,
        ffn1_w, ffn2_w, tr1_w, tr2_w, p2s_w, s2p_w, X, Wh, Xh, bq);
    // 1. fused qkv+gkv projection -> QKVG (bf16) + V^T side write
    gemm_k<<<dim3(NR*20), blk256, 0, stream>>>(
        Xh, Wh+OFF_QKV, 256, 256,  nullptr,nullptr,0,0,  nullptr,nullptr,0,0,
        bq, nullptr, 0, QKVG, 1280, 1, OP_NONE, 20, VTh);
    // 2. local_history (depthwise conv) -> LH bf16
    conv_k<<<dim3(M_*D_/256), blk256, 0, stream>>>(X, conv_w, conv_b, LH);
    // 3. banded attention (MFMA) -> MED bf16
    attn_k<<<dim3(T_/64, H_, B_), blk256, 0, stream>>>(QKVG, VTh, MED);
    // 4. mo projection -> MED2 bf16
    gemm_k<<<dim3(NR*4), blk256, 0, stream>>>(
        MED, Wh+OFF_MO, 256, 256,  nullptr,nullptr,0,0,  nullptr,nullptr,0,0,
        mo_b, nullptr, 0, MED2, 256, 1, OP_NONE, 4, nullptr);
    // 5. concepts scan -> CONC bf16
    scan1_p1<<<scan_grid, blk256, 0, stream>>>(QKVG, CAR0, CAR1);
    scan1_p2<<<dim3(4), blk256, 0, stream>>>(CAR0, CAR1);
    scan1_p3<<<scan_grid, blk256, 0, stream>>>(QKVG, CAR0, CAR1, CONC);
    // 6. global_out -> GOUT bf16
    gemm_k<<<dim3(NR*4), blk256, 0, stream>>>(
        CONC, Wh+OFF_GO, 256, 256,  nullptr,nullptr,0,0,  nullptr,nullptr,0,0,
        go_b, nullptr, 0, GOUT, 256, 1, OP_NONE, 4, nullptr);
    // 7. medium_out = MED2 * sigmoid([X,MED2]@fg^T + b) -> MOUT bf16
    gemm_k<<<dim3(NR*4), blk256, 0, stream>>>(
        Xh, Wh+OFF_FG, 512, 256,  MED2, Wh+OFF_FG+256, 512, 256,  nullptr,nullptr,0,0,
        fg_b, MED2, 1, MOUT, 256, 1, OP_SIGMUL, 4, nullptr);
    // 8. pre_ln1 = X + [LH,MOUT,GOUT]@comb^T + b -> PRE1 fp32
    gemm_k<<<dim3(NR*4), blk256, 0, stream>>>(
        LH, Wh+OFF_COMB, 768, 256,  MOUT, Wh+OFF_COMB+256, 768, 256,  GOUT, Wh+OFF_COMB+512, 768, 256,
        comb_b, X, 0, PRE1, 256, 0, OP_ADDAUX, 4, nullptr);
    // 9. pr = LN1 -> PR fp32 + PRh bf16
    ln_k<<<dim3(M_/4), blk256, 0, stream>>>(PRE1, ln1_g, ln1_b, PR, PRh);
    // 10. global_summary EMA -> GSUM bf16, final_traj -> out
    ema_p1<<<scan_grid, blk256, 0, stream>>>(PR, CAR0, 0.1f);
    ema_p2<<<dim3(4), blk256, 0, stream>>>(CAR0, out_tj);
    ema_p3h<<<scan_grid, blk256, 0, stream>>>(PR, CAR0, GSUM, 0.1f);
    // 11. cs1 = pr + 0.3*(pr@p2s^T + b) -> CS1 bf16
    gemm_k<<<dim3(NR*4), blk256, 0, stream>>>(
        PRh, Wh+OFF_P2S, 256, 256,  nullptr,nullptr,0,0,  nullptr,nullptr,0,0,
        p2s_b, PR, 0, CS1, 256, 1, OP_AXPBY, 4, nullptr);
    // 12. H1 = gelu(cs1@tr1a + gsum@tr1b + b) bf16
    gemm_k<<<dim3(NR*8), blk256, 0, stream>>>(
        CS1, Wh+OFF_TR1, 512, 256,  GSUM, Wh+OFF_TR1+256, 512, 256,  nullptr,nullptr,0,0,
        tr1_b, nullptr, 0, H1, 512, 1, OP_GELU, 8, nullptr);
    // 13. scaled = 0.5*tanh(H1@tr2^T + b) -> SCALED fp32
    gemm_k<<<dim3(NR*4), blk256, 0, stream>>>(
        H1, Wh+OFF_TR2, 512, 512,  nullptr,nullptr,0,0,  nullptr,nullptr,0,0,
        tr2_b, nullptr, 0, SCALED, 256, 0, OP_TANHHALF, 4, nullptr);
    // 14. state EMA + decayed initial -> PRE3 fp32
    ema_p1<<<scan_grid, blk256, 0, stream>>>(SCALED, CAR0, 1.0f);
    ema_p2<<<dim3(4), blk256, 0, stream>>>(CAR0, nullptr);
    ema_p3_state<<<scan_grid, blk256, 0, stream>>>(SCALED, CAR0, SEQ, PRE3);
    // 15. states = LN3 -> STATESh bf16; final_state = LN4(states[-1]) -> out
    ln3_k<<<dim3(M_/4), blk256, 0, stream>>>(PRE3, ln3_g, ln3_b, STATESh, ln4_g, ln4_b, out_fs);
    // 16. ffn_in = pr + 0.3*(states@s2p^T + b) -> FFNIN bf16
    gemm_k<<<dim3(NR*4), blk256, 0, stream>>>(
        STATESh, Wh+OFF_S2P, 256, 256,  nullptr,nullptr,0,0,  nullptr,nullptr,0,0,
        s2p_b, PR, 0, FFNIN, 256, 1, OP_AXPBY, 4, nullptr);
    // 17. H2 = gelu(ffn_in@ffn1^T + b) bf16
    gemm_k<<<dim3(NR*16), blk256, 0, stream>>>(
        FFNIN, Wh+OFF_FFN1, 256, 256,  nullptr,nullptr,0,0,  nullptr,nullptr,0,0,
        ffn1_b, nullptr, 0, H2, 1024, 1, OP_GELU, 16, nullptr);
    // 18. pre_ln2 = pr + H2@ffn2^T + b -> PRE2 fp32
    gemm_k<<<dim3(NR*4), blk256, 0, stream>>>(
        H2, Wh+OFF_FFN2, 1024, 1024,  nullptr,nullptr,0,0,  nullptr,nullptr,0,0,
        ffn2_b, PR, 0, PRE2, 256, 0, OP_ADDAUX, 4, nullptr);
    // 19. pr_out = LN2 -> d_out
    ln_k<<<dim3(M_/4), blk256, 0, stream>>>(PRE2, ln2_g, ln2_b, out_pr, nullptr);
}